// Round 19
// baseline (119.892 us; speedup 1.0000x reference)
//
#include <hip/hip_runtime.h>
#include <math.h>

typedef __attribute__((ext_vector_type(8))) short short8;
typedef __attribute__((ext_vector_type(8))) _Float16 half8;
typedef __attribute__((ext_vector_type(4))) float f32x4;
typedef __attribute__((ext_vector_type(16))) float f32x16;

#define NSP 4096
#define CIN 256
#define ICH 128
#define SPLITS 8
#define TPS 8
#define LOG2E 1.44269504088896f

__device__ __forceinline__ unsigned short f2h(float x){
  union { _Float16 h; unsigned short u; } v; v.h = (_Float16)x; return v.u;
}
__device__ __forceinline__ float h2f(unsigned short u){
  union { _Float16 h; unsigned short u; } v; v.u = u; return (float)v.h;
}
// pack two f32 -> two f16 in one u32 (v_cvt_pkrtz_f16_f32)
__device__ __forceinline__ unsigned pk2h(float a, float b){
  union { __fp16 __attribute__((ext_vector_type(2))) v; unsigned u; } r;
  r.v = __builtin_amdgcn_cvt_pkrtz(a, b);
  return r.u;
}
// raw 2^x via v_exp_f32
__device__ __forceinline__ float fexp2(float x){
  float r;
  asm("v_exp_f32 %0, %1" : "=v"(r) : "v"(x));
  return r;
}
// LDS swizzles (element units; 8-chunk preserving)
__device__ __forceinline__ int swz(int row, int e){ return e ^ ((row & 7) << 3); }    // 64-elem rows
__device__ __forceinline__ int swzK(int row, int e){ return e ^ ((row & 15) << 3); }  // 128-elem rows

__device__ __forceinline__ f32x4 mfmah(short8 a, short8 b, f32x4 c){
  union { short8 s; half8 h; } ua, ub; ua.s = a; ub.s = b;
  return __builtin_amdgcn_mfma_f32_16x16x32_f16(ua.h, ub.h, c, 0, 0, 0);
}
__device__ __forceinline__ f32x16 mfma32(short8 a, short8 b, f32x16 c){
  union { short8 s; half8 h; } ua, ub; ua.s = a; ub.s = b;
  return __builtin_amdgcn_mfma_f32_32x32x16_f16(ua.h, ub.h, c, 0, 0, 0);
}

// async global->LDS, 16B per lane. LDS dest = wave-uniform base + lane*16 (linear).
__device__ __forceinline__ void gload_lds16(const unsigned short* g, unsigned short* l){
  __builtin_amdgcn_global_load_lds(
      (const __attribute__((address_space(1))) unsigned int*)g,
      (__attribute__((address_space(3))) unsigned int*)l, 16, 0, 0);
}

// k-order permutation for PV with 32x32x16 A-fragments (see R16 derivation)
__device__ __forceinline__ int kperm(int q){
  int m = q & 15;
  return (q & 16) | (((m>>2)&1)<<3) | (m&3) | (((m>>3)&1)<<2);
}

// ---------------------------------------------------------------------------
// Fused 3-branch conv+BN+ReLU (R17: packed cvt_pkrtz staging).
// g written kperm-permuted; theta pre-scaled by log2(e).
// ---------------------------------------------------------------------------
__global__ __launch_bounds__(256) void conv_fused_k(
    const float* __restrict__ x,
    const float* __restrict__ w0, const float* __restrict__ b0,
    const float* __restrict__ ga0, const float* __restrict__ be0,
    const float* __restrict__ me0, const float* __restrict__ va0,
    const float* __restrict__ w1, const float* __restrict__ b1,
    const float* __restrict__ ga1, const float* __restrict__ be1,
    const float* __restrict__ me1, const float* __restrict__ va1,
    const float* __restrict__ w2, const float* __restrict__ b2,
    const float* __restrict__ ga2, const float* __restrict__ be2,
    const float* __restrict__ me2, const float* __restrict__ va2,
    unsigned short* __restrict__ outg, unsigned short* __restrict__ outt,
    unsigned short* __restrict__ outp)
{
  const int b = blockIdx.z, nt = blockIdx.x, ot = blockIdx.y;
  const int n0 = nt*64, o0 = ot*64;
  const int t = threadIdx.x, w = t>>6, l = t&63;
  __shared__ unsigned short xs[64][64];
  __shared__ unsigned short ws[3][64][64];
  __shared__ float sc_s[3][64], sh_s[3][64];
  if (t < 64){
    int o = o0 + t;
    float s0 = ga0[o]*rsqrtf(va0[o]+1e-5f);
    sc_s[0][t]=s0; sh_s[0][t]=be0[o]-me0[o]*s0+b0[o]*s0;
    float s1 = ga1[o]*rsqrtf(va1[o]+1e-5f);
    sc_s[1][t]=s1*LOG2E; sh_s[1][t]=(be1[o]-me1[o]*s1+b1[o]*s1)*LOG2E;
    float s2 = ga2[o]*rsqrtf(va2[o]+1e-5f);
    sc_s[2][t]=s2; sh_s[2][t]=be2[o]-me2[o]*s2+b2[o]*s2;
  }
  const f32x4 Z = {0.f,0.f,0.f,0.f};
  f32x4 acc[3][4];
  #pragma unroll
  for (int br=0;br<3;++br) for (int i=0;i<4;++i) acc[br][i] = Z;
  const float* Wt[3] = {w0, w1, w2};

  for (int kc = 0; kc < CIN; kc += 64){
    __syncthreads();
    #pragma unroll
    for (int p2 = 0; p2 < 2; ++p2){
      int cpr = p2*32 + 2*(t>>4);
      int nb = (t&15)*4;
      const float* xr0 = x + ((size_t)b*CIN + kc + cpr)*NSP + n0 + nb;
      float4 xa = *(const float4*)xr0;
      float4 xb = *(const float4*)(xr0 + NSP);
      float aa[4] = {xa.x, xa.y, xa.z, xa.w};
      float bb[4] = {xb.x, xb.y, xb.z, xb.w};
      #pragma unroll
      for (int i=0;i<4;++i){
        int r = nb + i;
        *(unsigned*)&xs[r][swz(r, cpr)] = pk2h(aa[i], bb[i]);
      }
    }
    #pragma unroll
    for (int p = 0; p < 4; ++p){
      int cw = p*16 + (t>>4);
      int q4 = (t&15)*4;
      #pragma unroll
      for (int br=0;br<3;++br){
        float4 wv = *(const float4*)(Wt[br] + (size_t)(o0 + cw)*CIN + kc + q4);
        uint2 u; u.x = pk2h(wv.x, wv.y); u.y = pk2h(wv.z, wv.w);
        *(uint2*)&ws[br][cw][swz(cw, q4)] = u;
      }
    }
    __syncthreads();
    #pragma unroll
    for (int kf = 0; kf < 2; ++kf){
      int ko = kf*32 + (l>>4)*8;
      int wr = 16*w + (l&15);
      short8 wf0 = *(const short8*)&ws[0][wr][swz(wr, ko)];
      short8 wf1 = *(const short8*)&ws[1][wr][swz(wr, ko)];
      short8 wf2 = *(const short8*)&ws[2][wr][swz(wr, ko)];
      #pragma unroll
      for (int nf = 0; nf < 4; ++nf){
        int xr = 16*nf + (l&15);
        short8 xf = *(const short8*)&xs[xr][swz(xr, ko)];
        acc[0][nf] = mfmah(wf0, xf, acc[0][nf]);
        acc[1][nf] = mfmah(xf, wf1, acc[1][nf]);
        acc[2][nf] = mfmah(xf, wf2, acc[2][nf]);
      }
    }
  }
  #pragma unroll
  for (int j=0;j<4;++j){
    int ol = 16*w + (l>>4)*4 + j;
    float s = sc_s[0][ol], sh = sh_s[0][ol];
    #pragma unroll
    for (int nf=0;nf<4;++nf){
      int n = n0 + 16*nf + (l&15);
      int nst = (n & ~31) | kperm(n & 31);
      float v = fmaxf(acc[0][nf][j]*s + sh, 0.f);
      outg[((size_t)b*ICH + o0 + ol)*NSP + nst] = f2h(v);
    }
  }
  {
    int ol = 16*w + (l&15);
    float s1 = sc_s[1][ol], sh1 = sh_s[1][ol];
    float s2 = sc_s[2][ol], sh2 = sh_s[2][ol];
    #pragma unroll
    for (int nf=0; nf<4; ++nf)
      #pragma unroll
      for (int j=0;j<4;++j){
        int n = n0 + 16*nf + (l>>4)*4 + j;
        float v1 = fmaxf(acc[1][nf][j]*s1 + sh1, 0.f);
        float v2 = fmaxf(acc[2][nf][j]*s2 + sh2, 0.f);
        outt[((size_t)b*NSP + n)*ICH + o0 + ol] = f2h(v1);
        outp[((size_t)b*NSP + n)*ICH + o0 + ol] = f2h(v2);
      }
  }
}

// ---------------------------------------------------------------------------
// Flash attention, 8 waves x 32 Q rows = Q256/block, 32x32x16 MFMA.
// Per-wave structure identical to R17 (104 VGPR) -> fits 128-VGPR cap at
// 4 waves/SIMD. 2 blocks/CU x 8 waves = 16 waves/CU. SPLITS=8, grid 512.
// ---------------------------------------------------------------------------
__global__ __launch_bounds__(512, 4) void attn_k(
  const unsigned short* __restrict__ thp, const unsigned short* __restrict__ php,
  const unsigned short* __restrict__ gb, unsigned short* __restrict__ ypart,
  float* __restrict__ ml)
{
  // decode: 32 combos (4b x 8s) x 16 qt; 4 combos per XCD
  const int bx = blockIdx.x;
  const int xcd = bx & 7, jj = bx >> 3;
  const int combo = xcd*4 + (jj>>4);
  const int qt = jj & 15;
  const int b = combo & 3, s = combo >> 2;
  const int n0 = qt*256;
  const int t = threadIdx.x, w = t>>6, l = t&63;
  const int hi = l>>5, ln = l&31;

  __shared__ unsigned short kb0a[8192];  // K dbuf 0 / Q chunk 0
  __shared__ unsigned short kb1a[8192];  // K dbuf 1 / Q chunk 1
  __shared__ unsigned short vb0a[8192];  // V dbuf 0 / Q chunk 2
  __shared__ unsigned short vb1a[8192];  // V dbuf 1 / Q chunk 3
  unsigned short* kb0 = kb0a;
  unsigned short* kb1 = kb1a;
  unsigned short* vb0 = vb0a;
  unsigned short* vb1 = vb1a;
  auto qsel = [&](int c) -> unsigned short* {
    return c==0 ? kb0 : (c==1 ? kb1 : (c==2 ? vb0 : vb1));
  };

  // ---- stage Q (256x128): chunk c = rows [64c,64c+64) ----
  #pragma unroll
  for (int c=0;c<4;++c){
    const unsigned short* src = thp + ((size_t)b*NSP + n0 + c*64)*ICH;
    unsigned short* dst = qsel(c) + w*1024;
    #pragma unroll
    for (int i=0;i<2;++i){
      int rl = 8*w + 4*i + (l>>4);
      int eg = ((l&15)*8) ^ ((rl&15)<<3);
      gload_lds16(src + (size_t)rl*128 + eg, dst + i*512);
    }
  }
  __syncthreads();
  short8 qf[8];
  {
    const unsigned short* qsrc = qsel(w>>1);
    int r = 32*(w&1) + ln;
    #pragma unroll
    for (int kc=0;kc<8;++kc)
      qf[kc] = *(const short8*)&qsrc[r*128 + swzK(r, kc*16 + 8*hi)];
  }
  __syncthreads();

  f32x16 oa[4];
  #pragma unroll
  for (int i=0;i<4;++i)
    #pragma unroll
    for (int j=0;j<16;++j) oa[i][j] = 0.f;
  float mr = -1e30f, lr = 0.f;
  unsigned pk[16];

  const int tile0 = s*TPS;

  // ---- hoisted per-lane staging pointers (2 loads/wave/tile) ----
  const unsigned short* kp[2];
  const unsigned short* vp[2];
  {
    const unsigned short* kbase = php + ((size_t)b*NSP + tile0*64)*ICH;
    const unsigned short* vbase = gb + (size_t)b*ICH*NSP + tile0*64;
    #pragma unroll
    for (int i=0;i<2;++i){
      int rl = 8*w + 4*i + (l>>4);
      int eg = ((l&15)*8) ^ ((rl&15)<<3);
      kp[i] = kbase + (size_t)rl*128 + eg;
      int cl = 16*w + 8*i + (l>>3);
      int me = ((l&7)*8) ^ ((cl&7)<<3);
      vp[i] = vbase + (size_t)cl*NSP + me;
    }
  }
  // prologue: stage tile0 into buffer 0
  {
    unsigned short* kd = kb0 + w*1024;
    unsigned short* vd = vb0 + w*1024;
    #pragma unroll
    for (int i=0;i<2;++i){
      gload_lds16(kp[i], kd + i*512); kp[i] += 64*ICH;
      gload_lds16(vp[i], vd + i*512); vp[i] += 64;
    }
  }
  __syncthreads();
  int cur = 0;

  for (int it = 0; it < TPS; ++it){
    unsigned short* kcur = cur ? kb1 : kb0;
    unsigned short* vcur = cur ? vb1 : vb0;
    // (A) prefetch next K+V
    if (it < TPS-1){
      unsigned short* kd = (cur ? kb0 : kb1) + w*1024;
      unsigned short* vd = (cur ? vb0 : vb1) + w*1024;
      #pragma unroll
      for (int i=0;i<2;++i){
        gload_lds16(kp[i], kd + i*512); kp[i] += 64*ICH;
        gload_lds16(vp[i], vd + i*512); vp[i] += 64;
      }
    }

    // (B) swapped QK^T: sc rows = m, cols = n. 16 mfma_32x32x16.
    f32x16 sc0, sc1;
    #pragma unroll
    for (int j=0;j<16;++j){ sc0[j]=0.f; sc1[j]=0.f; }
    __builtin_amdgcn_s_setprio(1);
    #pragma unroll
    for (int kc=0;kc<8;++kc){
      int eo = kc*16 + 8*hi;
      short8 a0 = *(const short8*)&kcur[(ln     )*128 + swzK(ln,      eo)];
      short8 a1 = *(const short8*)&kcur[(32 + ln)*128 + swzK(32 + ln, eo)];
      sc0 = mfma32(a0, qf[kc], sc0);
      sc1 = mfma32(a1, qf[kc], sc1);
    }
    __builtin_amdgcn_s_setprio(0);

    // (C1) max reduce + deferred rescale
    {
      float t0 = fmaxf(fmaxf(sc0[0],sc0[1]),  fmaxf(sc0[2],sc0[3]));
      float t1 = fmaxf(fmaxf(sc0[4],sc0[5]),  fmaxf(sc0[6],sc0[7]));
      float t2 = fmaxf(fmaxf(sc0[8],sc0[9]),  fmaxf(sc0[10],sc0[11]));
      float t3 = fmaxf(fmaxf(sc0[12],sc0[13]),fmaxf(sc0[14],sc0[15]));
      float t4 = fmaxf(fmaxf(sc1[0],sc1[1]),  fmaxf(sc1[2],sc1[3]));
      float t5 = fmaxf(fmaxf(sc1[4],sc1[5]),  fmaxf(sc1[6],sc1[7]));
      float t6 = fmaxf(fmaxf(sc1[8],sc1[9]),  fmaxf(sc1[10],sc1[11]));
      float t7 = fmaxf(fmaxf(sc1[12],sc1[13]),fmaxf(sc1[14],sc1[15]));
      float mx = fmaxf(fmaxf(fmaxf(t0,t1),fmaxf(t2,t3)),
                       fmaxf(fmaxf(t4,t5),fmaxf(t6,t7)));
      mx = fmaxf(mx, __shfl_xor(mx, 32));
      if (__any(mx - mr > 11.5f)){
        float mn = fmaxf(mr, mx);
        float al = fexp2(mr - mn);
        mr = mn; lr *= al;
        #pragma unroll
        for (int j=0;j<16;++j){
          int rowj = (j&3) + 8*(j>>2) + 4*hi;
          float alj = __shfl(al, rowj);
          #pragma unroll
          for (int ct=0;ct<4;++ct) oa[ct][j] *= alj;
        }
      }
    }

    float sA=0.f, sB=0.f, sC=0.f, sD=0.f;
    // (C2a) exp sc0 + pack
    #pragma unroll
    for (int r=0;r<16;r+=4){
      sc0[r]   = fexp2(sc0[r]  -mr); sA += sc0[r];
      sc0[r+1] = fexp2(sc0[r+1]-mr); sB += sc0[r+1];
      sc0[r+2] = fexp2(sc0[r+2]-mr); sC += sc0[r+2];
      sc0[r+3] = fexp2(sc0[r+3]-mr); sD += sc0[r+3];
    }
    #pragma unroll
    for (int s2=0;s2<2;++s2)
      #pragma unroll
      for (int q=0;q<4;++q)
        pk[s2*4+q] = pk2h(sc0[8*s2+2*q], sc0[8*s2+2*q+1]);
    // (D-a) PV for sc0's m-rows
    __builtin_amdgcn_s_setprio(1);
    #pragma unroll
    for (int s2=0;s2<2;++s2){
      union { unsigned u[4]; short8 s8; } au;
      #pragma unroll
      for (int q=0;q<4;++q) au.u[q] = pk[4*s2+q];
      int eo = 16*s2 + 8*hi;
      #pragma unroll
      for (int ct=0;ct<4;++ct){
        int cr = 32*ct + ln;
        short8 bv = *(const short8*)&vcur[cr*64 + swz(cr, eo)];
        oa[ct] = mfma32(au.s8, bv, oa[ct]);
      }
    }
    __builtin_amdgcn_s_setprio(0);
    // (C2b) exp sc1 + pack
    #pragma unroll
    for (int r=0;r<16;r+=4){
      sc1[r]   = fexp2(sc1[r]  -mr); sA += sc1[r];
      sc1[r+1] = fexp2(sc1[r+1]-mr); sB += sc1[r+1];
      sc1[r+2] = fexp2(sc1[r+2]-mr); sC += sc1[r+2];
      sc1[r+3] = fexp2(sc1[r+3]-mr); sD += sc1[r+3];
    }
    #pragma unroll
    for (int s2=0;s2<2;++s2)
      #pragma unroll
      for (int q=0;q<4;++q)
        pk[8+s2*4+q] = pk2h(sc1[8*s2+2*q], sc1[8*s2+2*q+1]);
    lr += (sA + sB) + (sC + sD);
    // (D-b) PV for sc1's m-rows
    __builtin_amdgcn_s_setprio(1);
    #pragma unroll
    for (int s2=0;s2<2;++s2){
      union { unsigned u[4]; short8 s8; } au;
      #pragma unroll
      for (int q=0;q<4;++q) au.u[q] = pk[8+4*s2+q];
      int eo = 32 + 16*s2 + 8*hi;
      #pragma unroll
      for (int ct=0;ct<4;++ct){
        int cr = 32*ct + ln;
        short8 bv = *(const short8*)&vcur[cr*64 + swz(cr, eo)];
        oa[ct] = mfma32(au.s8, bv, oa[ct]);
      }
    }
    __builtin_amdgcn_s_setprio(0);

    __syncthreads();
    cur ^= 1;
  }

  // ---- epilogue ----
  lr += __shfl_xor(lr, 32);
  float invl = 1.f / lr;
  #pragma unroll
  for (int j=0;j<16;++j){
    int rowj = (j&3) + 8*(j>>2) + 4*hi;
    float invj = __shfl(invl, rowj);
    int n = n0 + 32*w + rowj;
    #pragma unroll
    for (int ct=0;ct<4;++ct){
      int c = 32*ct + ln;
      ypart[(((size_t)s*4 + b)*NSP + n)*ICH + c] = f2h(oa[ct][j]*invj);
    }
  }
  if (l < 32){
    int n = n0 + 32*w + l;
    ml[(((size_t)s*4 + b)*NSP + n)*2 + 0] = mr;
    ml[(((size_t)s*4 + b)*NSP + n)*2 + 1] = lr;
  }
}

// ---------------------------------------------------------------------------
// Final conv + fused split-combine, 2 o-tiles per block, SPL=8 combine.
// ---------------------------------------------------------------------------
__global__ __launch_bounds__(256) void final_k2(
  const unsigned short* __restrict__ ypart, const float* __restrict__ ml,
  const float* __restrict__ x, const float* __restrict__ Wm,
  const float* __restrict__ bias, const float* __restrict__ gamma,
  const float* __restrict__ beta, const float* __restrict__ mean,
  const float* __restrict__ var, float* __restrict__ out)
{
  const int b = blockIdx.z, oth = blockIdx.y, nt = blockIdx.x;
  const int n0 = nt*64, obase = oth*128;
  const int t = threadIdx.x, w = t>>6, l = t&63;
  __shared__ unsigned short ys[64][128];
  __shared__ unsigned short w2s[64][128];
  __shared__ float wc[SPLITS][64];
  __shared__ float sc_s[128], sh_s[128];
  if (t < 128){
    int o = obase + t;
    float s = gamma[o]*rsqrtf(var[o]+1e-5f);
    sc_s[t]=s; sh_s[t]=beta[o]-mean[o]*s+bias[o]*s;
  } else if (t < 192){
    int r = t - 128, n = n0 + r;
    float mv[SPLITS], lv[SPLITS];
    #pragma unroll
    for (int s=0;s<SPLITS;++s){
      mv[s] = ml[(((size_t)s*4 + b)*NSP + n)*2 + 0];
      lv[s] = ml[(((size_t)s*4 + b)*NSP + n)*2 + 1];
    }
    float M = mv[0];
    #pragma unroll
    for (int s=1;s<SPLITS;++s) M = fmaxf(M, mv[s]);
    float wsum = 0.f, wv[SPLITS];
    #pragma unroll
    for (int s=0;s<SPLITS;++s){ wv[s] = lv[s]*exp2f(mv[s]-M); wsum += wv[s]; }
    float inv = 1.f/wsum;
    #pragma unroll
    for (int s=0;s<SPLITS;++s) wc[s][r] = wv[s]*inv;
  }
  __syncthreads();
  #pragma unroll
  for (int p=0;p<4;++p){
    int id = p*256 + t, r = id>>4, c8 = (id&15)*8;
    float accv[8] = {0,0,0,0,0,0,0,0};
    #pragma unroll
    for (int s=0;s<SPLITS;++s){
      short8 v = *(const short8*)(ypart + (((size_t)s*4 + b)*NSP + n0 + r)*ICH + c8);
      float wgt = wc[s][r];
      #pragma unroll
      for (int i=0;i<8;++i) accv[i] += wgt * h2f(((unsigned short*)&v)[i]);
    }
    unsigned short hv[8];
    #pragma unroll
    for (int i=0;i<8;++i) hv[i] = f2h(accv[i]);
    *(short8*)&ys[r][swz(r,c8)] = *(short8*)hv;
  }

  const f32x4 Z = {0.f,0.f,0.f,0.f};
  #pragma unroll
  for (int ot2 = 0; ot2 < 2; ++ot2){
    const int o0 = obase + ot2*64;
    #pragma unroll
    for (int p=0;p<4;++p){
      int id = p*256 + t, r = id>>4, c8 = (id&15)*8;
      float4 u0 = *(const float4*)(Wm + (size_t)(o0 + r)*ICH + c8);
      float4 u1 = *(const float4*)(Wm + (size_t)(o0 + r)*ICH + c8 + 4);
      uint2 u; u.x = pk2h(u0.x, u0.y); u.y = pk2h(u0.z, u0.w);
      uint2 v2; v2.x = pk2h(u1.x, u1.y); v2.y = pk2h(u1.z, u1.w);
      *(uint2*)&w2s[r][swz(r,c8)] = u;
      *(uint2*)&w2s[r][swz(r,c8)+4] = v2;
    }
    __syncthreads();
    f32x4 acc[4];
    #pragma unroll
    for (int i=0;i<4;++i) acc[i]=Z;
    #pragma unroll
    for (int kf=0;kf<4;++kf){
      int ko = kf*32 + (l>>4)*8;
      int wr = 16*w + (l&15);
      short8 a = *(const short8*)&w2s[wr][swz(wr,ko)];
      #pragma unroll
      for (int nf=0;nf<4;++nf){
        int yr = 16*nf + (l&15);
        short8 bb = *(const short8*)&ys[yr][swz(yr,ko)];
        acc[nf] = mfmah(a, bb, acc[nf]);
      }
    }
    #pragma unroll
    for (int j=0;j<4;++j){
      int ol = 16*w + (l>>4)*4 + j;
      float s = sc_s[ot2*64 + ol], sh = sh_s[ot2*64 + ol];
      #pragma unroll
      for (int nf=0;nf<4;++nf){
        int n = n0 + 16*nf + (l&15);
        size_t idx = ((size_t)b*CIN + o0 + ol)*NSP + n;
        out[idx] = acc[nf][j]*s + sh + x[idx];
      }
    }
    __syncthreads();
  }
}

extern "C" void kernel_launch(void* const* d_in, const int* in_sizes, int n_in,
                              void* d_out, int out_size, void* d_ws, size_t ws_size,
                              hipStream_t stream){
  const float* x    = (const float*)d_in[0];
  const float* g_w  = (const float*)d_in[1];
  const float* g_b  = (const float*)d_in[2];
  const float* g_ga = (const float*)d_in[3];
  const float* g_be = (const float*)d_in[4];
  const float* g_me = (const float*)d_in[5];
  const float* g_va = (const float*)d_in[6];
  const float* t_w  = (const float*)d_in[7];
  const float* t_b  = (const float*)d_in[8];
  const float* t_ga = (const float*)d_in[9];
  const float* t_be = (const float*)d_in[10];
  const float* t_me = (const float*)d_in[11];
  const float* t_va = (const float*)d_in[12];
  const float* p_w  = (const float*)d_in[13];
  const float* p_b  = (const float*)d_in[14];
  const float* p_ga = (const float*)d_in[15];
  const float* p_be = (const float*)d_in[16];
  const float* p_me = (const float*)d_in[17];
  const float* p_va = (const float*)d_in[18];
  const float* w_w  = (const float*)d_in[19];
  const float* w_b  = (const float*)d_in[20];
  const float* w_ga = (const float*)d_in[21];
  const float* w_be = (const float*)d_in[22];
  const float* w_me = (const float*)d_in[23];
  const float* w_va = (const float*)d_in[24];

  char* ws = (char*)d_ws;
  const size_t SEG = (size_t)4*NSP*ICH*sizeof(unsigned short);   // 4 MB
  unsigned short* th_t  = (unsigned short*)(ws);
  unsigned short* ph_t  = (unsigned short*)(ws + SEG);
  unsigned short* g_cn  = (unsigned short*)(ws + 2*SEG);
  unsigned short* ypart = (unsigned short*)(ws + 3*SEG);
  float*          mlb   = (float*)(ws + 3*SEG + SPLITS*SEG);

  dim3 blk(256,1,1);
  conv_fused_k<<<dim3(64,2,4), blk, 0, stream>>>(
      x,
      g_w, g_b, g_ga, g_be, g_me, g_va,
      t_w, t_b, t_ga, t_be, t_me, t_va,
      p_w, p_b, p_ga, p_be, p_me, p_va,
      g_cn, th_t, ph_t);
  attn_k<<<dim3(512,1,1), dim3(512,1,1), 0, stream>>>(th_t, ph_t, g_cn, ypart, mlb);
  final_k2<<<dim3(64,2,4), blk, 0, stream>>>(ypart, mlb, x, w_w, w_b, w_ga, w_be, w_me, w_va, (float*)d_out);
}

// Round 20
// 69.357 us; speedup vs baseline: 1.7286x; 1.7286x over previous
//
#include <hip/hip_runtime.h>
#include <math.h>

typedef __attribute__((ext_vector_type(8))) short short8;
typedef __attribute__((ext_vector_type(8))) _Float16 half8;
typedef __attribute__((ext_vector_type(4))) float f32x4;
typedef __attribute__((ext_vector_type(16))) float f32x16;

#define NSP 4096
#define CIN 256
#define ICH 128
#define SPLITS 4
#define TILES_PER_SPLIT 16
#define LOG2E 1.44269504088896f

__device__ __forceinline__ unsigned short f2h(float x){
  union { _Float16 h; unsigned short u; } v; v.h = (_Float16)x; return v.u;
}
__device__ __forceinline__ float h2f(unsigned short u){
  union { _Float16 h; unsigned short u; } v; v.u = u; return (float)v.h;
}
// pack two f32 -> two f16 in one u32 (v_cvt_pkrtz_f16_f32)
__device__ __forceinline__ unsigned pk2h(float a, float b){
  union { __fp16 __attribute__((ext_vector_type(2))) v; unsigned u; } r;
  r.v = __builtin_amdgcn_cvt_pkrtz(a, b);
  return r.u;
}
// raw 2^x via v_exp_f32
__device__ __forceinline__ float fexp2(float x){
  float r;
  asm("v_exp_f32 %0, %1" : "=v"(r) : "v"(x));
  return r;
}
// LDS swizzles (element units; 8-chunk preserving)
__device__ __forceinline__ int swz(int row, int e){ return e ^ ((row & 7) << 3); }    // 64-elem rows
__device__ __forceinline__ int swzK(int row, int e){ return e ^ ((row & 15) << 3); }  // 128-elem rows

__device__ __forceinline__ f32x4 mfmah(short8 a, short8 b, f32x4 c){
  union { short8 s; half8 h; } ua, ub; ua.s = a; ub.s = b;
  return __builtin_amdgcn_mfma_f32_16x16x32_f16(ua.h, ub.h, c, 0, 0, 0);
}
__device__ __forceinline__ f32x16 mfma32(short8 a, short8 b, f32x16 c){
  union { short8 s; half8 h; } ua, ub; ua.s = a; ub.s = b;
  return __builtin_amdgcn_mfma_f32_32x32x16_f16(ua.h, ub.h, c, 0, 0, 0);
}

// async global->LDS, 16B per lane. LDS dest = wave-uniform base + lane*16 (linear).
__device__ __forceinline__ void gload_lds16(const unsigned short* g, unsigned short* l){
  __builtin_amdgcn_global_load_lds(
      (const __attribute__((address_space(1))) unsigned int*)g,
      (__attribute__((address_space(3))) unsigned int*)l, 16, 0, 0);
}

// Stage a 64x128 fp16 tile into LDS flat [64][128], swzK pre-applied on SOURCE.
__device__ __forceinline__ void stage_nc(const unsigned short* gbase, unsigned short* lds,
                                         int w, int l){
  #pragma unroll
  for (int i=0;i<4;++i){
    int rl = 16*w + 4*i + (l>>4);
    int eg = ((l&15)*8) ^ ((rl&15)<<3);
    gload_lds16(gbase + (size_t)rl*128 + eg, lds + w*2048 + i*512);
  }
}

// k-order permutation for PV with 32x32x16 A-fragments (see R16 derivation)
__device__ __forceinline__ int kperm(int q){
  int m = q & 15;
  return (q & 16) | (((m>>2)&1)<<3) | (m&3) | (((m>>3)&1)<<2);
}

// ---------------------------------------------------------------------------
// Fused 3-branch conv+BN+ReLU: reads x once, computes g/theta/phi tiles.
// Staging uses packed cvt_pkrtz + b32/b64 LDS stores.
// g written kperm-permuted; theta pre-scaled by log2(e).
// ---------------------------------------------------------------------------
__global__ __launch_bounds__(256) void conv_fused_k(
    const float* __restrict__ x,
    const float* __restrict__ w0, const float* __restrict__ b0,
    const float* __restrict__ ga0, const float* __restrict__ be0,
    const float* __restrict__ me0, const float* __restrict__ va0,
    const float* __restrict__ w1, const float* __restrict__ b1,
    const float* __restrict__ ga1, const float* __restrict__ be1,
    const float* __restrict__ me1, const float* __restrict__ va1,
    const float* __restrict__ w2, const float* __restrict__ b2,
    const float* __restrict__ ga2, const float* __restrict__ be2,
    const float* __restrict__ me2, const float* __restrict__ va2,
    unsigned short* __restrict__ outg, unsigned short* __restrict__ outt,
    unsigned short* __restrict__ outp)
{
  const int b = blockIdx.z, nt = blockIdx.x, ot = blockIdx.y;
  const int n0 = nt*64, o0 = ot*64;
  const int t = threadIdx.x, w = t>>6, l = t&63;
  __shared__ unsigned short xs[64][64];
  __shared__ unsigned short ws[3][64][64];
  __shared__ float sc_s[3][64], sh_s[3][64];
  if (t < 64){
    int o = o0 + t;
    float s0 = ga0[o]*rsqrtf(va0[o]+1e-5f);
    sc_s[0][t]=s0; sh_s[0][t]=be0[o]-me0[o]*s0+b0[o]*s0;
    float s1 = ga1[o]*rsqrtf(va1[o]+1e-5f);
    sc_s[1][t]=s1*LOG2E; sh_s[1][t]=(be1[o]-me1[o]*s1+b1[o]*s1)*LOG2E;
    float s2 = ga2[o]*rsqrtf(va2[o]+1e-5f);
    sc_s[2][t]=s2; sh_s[2][t]=be2[o]-me2[o]*s2+b2[o]*s2;
  }
  const f32x4 Z = {0.f,0.f,0.f,0.f};
  f32x4 acc[3][4];
  #pragma unroll
  for (int br=0;br<3;++br) for (int i=0;i<4;++i) acc[br][i] = Z;
  const float* Wt[3] = {w0, w1, w2};

  for (int kc = 0; kc < CIN; kc += 64){
    __syncthreads();
    // x tile: global [c][n] -> LDS [n][c], c-pair-packed b32 stores
    #pragma unroll
    for (int p2 = 0; p2 < 2; ++p2){
      int cpr = p2*32 + 2*(t>>4);        // even c of the pair
      int nb = (t&15)*4;
      const float* xr0 = x + ((size_t)b*CIN + kc + cpr)*NSP + n0 + nb;
      float4 xa = *(const float4*)xr0;
      float4 xb = *(const float4*)(xr0 + NSP);
      float aa[4] = {xa.x, xa.y, xa.z, xa.w};
      float bb[4] = {xb.x, xb.y, xb.z, xb.w};
      #pragma unroll
      for (int i=0;i<4;++i){
        int r = nb + i;
        *(unsigned*)&xs[r][swz(r, cpr)] = pk2h(aa[i], bb[i]);
      }
    }
    // W tiles: packed cvt + b64 stores
    #pragma unroll
    for (int p = 0; p < 4; ++p){
      int cw = p*16 + (t>>4);
      int q4 = (t&15)*4;
      #pragma unroll
      for (int br=0;br<3;++br){
        float4 wv = *(const float4*)(Wt[br] + (size_t)(o0 + cw)*CIN + kc + q4);
        uint2 u; u.x = pk2h(wv.x, wv.y); u.y = pk2h(wv.z, wv.w);
        *(uint2*)&ws[br][cw][swz(cw, q4)] = u;
      }
    }
    __syncthreads();
    #pragma unroll
    for (int kf = 0; kf < 2; ++kf){
      int ko = kf*32 + (l>>4)*8;
      int wr = 16*w + (l&15);
      short8 wf0 = *(const short8*)&ws[0][wr][swz(wr, ko)];
      short8 wf1 = *(const short8*)&ws[1][wr][swz(wr, ko)];
      short8 wf2 = *(const short8*)&ws[2][wr][swz(wr, ko)];
      #pragma unroll
      for (int nf = 0; nf < 4; ++nf){
        int xr = 16*nf + (l&15);
        short8 xf = *(const short8*)&xs[xr][swz(xr, ko)];
        acc[0][nf] = mfmah(wf0, xf, acc[0][nf]);   // orient0 (g)
        acc[1][nf] = mfmah(xf, wf1, acc[1][nf]);   // orient1 (theta)
        acc[2][nf] = mfmah(xf, wf2, acc[2][nf]);   // orient1 (phi)
      }
    }
  }
  // g epilogue (orient0, kperm-permuted column order)
  #pragma unroll
  for (int j=0;j<4;++j){
    int ol = 16*w + (l>>4)*4 + j;
    float s = sc_s[0][ol], sh = sh_s[0][ol];
    #pragma unroll
    for (int nf=0;nf<4;++nf){
      int n = n0 + 16*nf + (l&15);
      int nst = (n & ~31) | kperm(n & 31);
      float v = fmaxf(acc[0][nf][j]*s + sh, 0.f);
      outg[((size_t)b*ICH + o0 + ol)*NSP + nst] = f2h(v);
    }
  }
  // theta/phi epilogue (orient1)
  {
    int ol = 16*w + (l&15);
    float s1 = sc_s[1][ol], sh1 = sh_s[1][ol];
    float s2 = sc_s[2][ol], sh2 = sh_s[2][ol];
    #pragma unroll
    for (int nf=0; nf<4; ++nf)
      #pragma unroll
      for (int j=0;j<4;++j){
        int n = n0 + 16*nf + (l>>4)*4 + j;
        float v1 = fmaxf(acc[1][nf][j]*s1 + sh1, 0.f);
        float v2 = fmaxf(acc[2][nf][j]*s2 + sh2, 0.f);
        outt[((size_t)b*NSP + n)*ICH + o0 + ol] = f2h(v1);
        outp[((size_t)b*NSP + n)*ICH + o0 + ol] = f2h(v2);
      }
  }
}

// ---------------------------------------------------------------------------
// Flash attention, 32x32x16 MFMA, 4 waves x 32 Q rows. Softmax/PV interleaved:
// exp(sc0)+pack -> PV-a, exp(sc1)+pack -> PV-b (trans pipe overlaps matrix).
// ---------------------------------------------------------------------------
__global__ __launch_bounds__(256, 2) void attn_k(
  const unsigned short* __restrict__ thp, const unsigned short* __restrict__ php,
  const unsigned short* __restrict__ gb, unsigned short* __restrict__ ypart,
  float* __restrict__ ml)
{
  const int bx = blockIdx.x;
  const int xcd = bx & 7, jj = bx >> 3;
  const int combo = xcd*2 + (jj>>5);
  const int qt = jj & 31;
  const int b = combo & 3, s = combo >> 2;
  const int n0 = qt*128;
  const int t = threadIdx.x, w = t>>6, l = t&63;
  const int hi = l>>5, ln = l&31;

  __shared__ unsigned short kb[2][8192];   // K double buffer [64][128]
  __shared__ unsigned short vb[2][8192];   // V double buffer [128][64]

  // ---- stage Q halves through kb[0]/kb[1], preload 8 B-fragments ----
  stage_nc(thp + ((size_t)b*NSP + n0      )*ICH, &kb[0][0], w, l);
  stage_nc(thp + ((size_t)b*NSP + n0 + 64 )*ICH, &kb[1][0], w, l);
  __syncthreads();
  short8 qf[8];
  {
    const unsigned short* qsrc = (w >> 1) ? &kb[1][0] : &kb[0][0];
    int r = 32*(w & 1) + ln;
    #pragma unroll
    for (int kc=0;kc<8;++kc)
      qf[kc] = *(const short8*)&qsrc[r*128 + swzK(r, kc*16 + 8*hi)];
  }
  __syncthreads();

  f32x16 oa[4];
  #pragma unroll
  for (int i=0;i<4;++i)
    #pragma unroll
    for (int j=0;j<16;++j) oa[i][j] = 0.f;
  float mr = -1e30f, lr = 0.f;
  unsigned pk[16];

  const int tile0 = s*TILES_PER_SPLIT;

  // ---- hoisted per-lane staging pointers ----
  const unsigned short* kp[4];
  const unsigned short* vp[4];
  {
    const unsigned short* kbase = php + ((size_t)b*NSP + tile0*64)*ICH;
    const unsigned short* vbase = gb + (size_t)b*ICH*NSP + tile0*64;
    #pragma unroll
    for (int i=0;i<4;++i){
      int rl = 16*w + 4*i + (l>>4);
      int eg = ((l&15)*8) ^ ((rl&15)<<3);
      kp[i] = kbase + (size_t)rl*128 + eg;
      int cl = 32*w + 8*i + (l>>3);
      int me = ((l&7)*8) ^ ((cl&7)<<3);
      vp[i] = vbase + (size_t)cl*NSP + me;
    }
  }
  // prologue: stage tile0 into buffer 0
  {
    unsigned short* kd = &kb[0][0] + w*2048;
    unsigned short* vd = &vb[0][0] + w*2048;
    #pragma unroll
    for (int i=0;i<4;++i){
      gload_lds16(kp[i], kd + i*512); kp[i] += 64*ICH;
      gload_lds16(vp[i], vd + i*512); vp[i] += 64;
    }
  }
  __syncthreads();
  int cur = 0;

  for (int it = 0; it < TILES_PER_SPLIT; ++it){
    // (A) prefetch next K+V
    if (it < TILES_PER_SPLIT-1){
      unsigned short* kd = &kb[cur^1][0] + w*2048;
      unsigned short* vd = &vb[cur^1][0] + w*2048;
      #pragma unroll
      for (int i=0;i<4;++i){
        gload_lds16(kp[i], kd + i*512); kp[i] += 64*ICH;
        gload_lds16(vp[i], vd + i*512); vp[i] += 64;
      }
    }

    // (B) swapped QK^T: sc rows = m, cols = n. 16 mfma_32x32x16.
    f32x16 sc0, sc1;
    #pragma unroll
    for (int j=0;j<16;++j){ sc0[j]=0.f; sc1[j]=0.f; }
    __builtin_amdgcn_s_setprio(1);
    #pragma unroll
    for (int kc=0;kc<8;++kc){
      int eo = kc*16 + 8*hi;
      short8 a0 = *(const short8*)&kb[cur][(ln     )*128 + swzK(ln,      eo)];
      short8 a1 = *(const short8*)&kb[cur][(32 + ln)*128 + swzK(32 + ln, eo)];
      sc0 = mfma32(a0, qf[kc], sc0);
      sc1 = mfma32(a1, qf[kc], sc1);
    }
    __builtin_amdgcn_s_setprio(0);

    // (C1) max reduce + deferred rescale
    {
      float t0 = fmaxf(fmaxf(sc0[0],sc0[1]),  fmaxf(sc0[2],sc0[3]));
      float t1 = fmaxf(fmaxf(sc0[4],sc0[5]),  fmaxf(sc0[6],sc0[7]));
      float t2 = fmaxf(fmaxf(sc0[8],sc0[9]),  fmaxf(sc0[10],sc0[11]));
      float t3 = fmaxf(fmaxf(sc0[12],sc0[13]),fmaxf(sc0[14],sc0[15]));
      float t4 = fmaxf(fmaxf(sc1[0],sc1[1]),  fmaxf(sc1[2],sc1[3]));
      float t5 = fmaxf(fmaxf(sc1[4],sc1[5]),  fmaxf(sc1[6],sc1[7]));
      float t6 = fmaxf(fmaxf(sc1[8],sc1[9]),  fmaxf(sc1[10],sc1[11]));
      float t7 = fmaxf(fmaxf(sc1[12],sc1[13]),fmaxf(sc1[14],sc1[15]));
      float mx = fmaxf(fmaxf(fmaxf(t0,t1),fmaxf(t2,t3)),
                       fmaxf(fmaxf(t4,t5),fmaxf(t6,t7)));
      mx = fmaxf(mx, __shfl_xor(mx, 32));
      if (__any(mx - mr > 11.5f)){   // defer-max (log2 units)
        float mn = fmaxf(mr, mx);
        float al = fexp2(mr - mn);
        mr = mn; lr *= al;
        #pragma unroll
        for (int j=0;j<16;++j){
          int rowj = (j&3) + 8*(j>>2) + 4*hi;
          float alj = __shfl(al, rowj);
          #pragma unroll
          for (int ct=0;ct<4;++ct) oa[ct][j] *= alj;
        }
      }
    }

    float sA=0.f, sB=0.f, sC=0.f, sD=0.f;
    // (C2a) exp sc0 + pack pk[0..7]
    #pragma unroll
    for (int r=0;r<16;r+=4){
      sc0[r]   = fexp2(sc0[r]  -mr); sA += sc0[r];
      sc0[r+1] = fexp2(sc0[r+1]-mr); sB += sc0[r+1];
      sc0[r+2] = fexp2(sc0[r+2]-mr); sC += sc0[r+2];
      sc0[r+3] = fexp2(sc0[r+3]-mr); sD += sc0[r+3];
    }
    #pragma unroll
    for (int s2=0;s2<2;++s2)
      #pragma unroll
      for (int q=0;q<4;++q)
        pk[s2*4+q] = pk2h(sc0[8*s2+2*q], sc0[8*s2+2*q+1]);
    // (D-a) PV for sc0's m-rows (overlappable with C2b below)
    __builtin_amdgcn_s_setprio(1);
    #pragma unroll
    for (int s2=0;s2<2;++s2){
      union { unsigned u[4]; short8 s8; } au;
      #pragma unroll
      for (int q=0;q<4;++q) au.u[q] = pk[4*s2+q];
      int eo = 16*s2 + 8*hi;
      #pragma unroll
      for (int ct=0;ct<4;++ct){
        int cr = 32*ct + ln;
        short8 bv = *(const short8*)&vb[cur][cr*64 + swz(cr, eo)];
        oa[ct] = mfma32(au.s8, bv, oa[ct]);
      }
    }
    __builtin_amdgcn_s_setprio(0);
    // (C2b) exp sc1 + pack pk[8..15]
    #pragma unroll
    for (int r=0;r<16;r+=4){
      sc1[r]   = fexp2(sc1[r]  -mr); sA += sc1[r];
      sc1[r+1] = fexp2(sc1[r+1]-mr); sB += sc1[r+1];
      sc1[r+2] = fexp2(sc1[r+2]-mr); sC += sc1[r+2];
      sc1[r+3] = fexp2(sc1[r+3]-mr); sD += sc1[r+3];
    }
    #pragma unroll
    for (int s2=0;s2<2;++s2)
      #pragma unroll
      for (int q=0;q<4;++q)
        pk[8+s2*4+q] = pk2h(sc1[8*s2+2*q], sc1[8*s2+2*q+1]);
    lr += (sA + sB) + (sC + sD);
    // (D-b) PV for sc1's m-rows
    __builtin_amdgcn_s_setprio(1);
    #pragma unroll
    for (int s2=0;s2<2;++s2){
      union { unsigned u[4]; short8 s8; } au;
      #pragma unroll
      for (int q=0;q<4;++q) au.u[q] = pk[8+4*s2+q];
      int eo = 32 + 16*s2 + 8*hi;
      #pragma unroll
      for (int ct=0;ct<4;++ct){
        int cr = 32*ct + ln;
        short8 bv = *(const short8*)&vb[cur][cr*64 + swz(cr, eo)];
        oa[ct] = mfma32(au.s8, bv, oa[ct]);
      }
    }
    __builtin_amdgcn_s_setprio(0);

    __syncthreads();
    cur ^= 1;
  }

  // ---- epilogue: combine partner sums, normalize, write ----
  lr += __shfl_xor(lr, 32);
  float invl = 1.f / lr;
  #pragma unroll
  for (int j=0;j<16;++j){
    int rowj = (j&3) + 8*(j>>2) + 4*hi;
    float invj = __shfl(invl, rowj);
    int n = n0 + 32*w + rowj;
    #pragma unroll
    for (int ct=0;ct<4;++ct){
      int c = 32*ct + ln;
      ypart[(((size_t)s*4 + b)*NSP + n)*ICH + c] = f2h(oa[ct][j]*invj);
    }
  }
  if (l < 32){
    int n = n0 + 32*w + l;
    ml[(((size_t)s*4 + b)*NSP + n)*2 + 0] = mr;
    ml[(((size_t)s*4 + b)*NSP + n)*2 + 1] = lr;
  }
}

// ---------------------------------------------------------------------------
// Final conv + fused split-combine, 2 o-tiles per block (R15 final_k2)
// ---------------------------------------------------------------------------
__global__ __launch_bounds__(256) void final_k2(
  const unsigned short* __restrict__ ypart, const float* __restrict__ ml,
  const float* __restrict__ x, const float* __restrict__ Wm,
  const float* __restrict__ bias, const float* __restrict__ gamma,
  const float* __restrict__ beta, const float* __restrict__ mean,
  const float* __restrict__ var, float* __restrict__ out)
{
  const int b = blockIdx.z, oth = blockIdx.y, nt = blockIdx.x;
  const int n0 = nt*64, obase = oth*128;
  const int t = threadIdx.x, w = t>>6, l = t&63;
  __shared__ unsigned short ys[64][128];
  __shared__ unsigned short w2s[64][128];
  __shared__ float wc[SPLITS][64];
  __shared__ float sc_s[128], sh_s[128];
  if (t < 128){
    int o = obase + t;
    float s = gamma[o]*rsqrtf(var[o]+1e-5f);
    sc_s[t]=s; sh_s[t]=beta[o]-mean[o]*s+bias[o]*s;
  } else if (t < 192){
    int r = t - 128, n = n0 + r;
    float mv[SPLITS], lv[SPLITS];
    #pragma unroll
    for (int s=0;s<SPLITS;++s){
      mv[s] = ml[(((size_t)s*4 + b)*NSP + n)*2 + 0];
      lv[s] = ml[(((size_t)s*4 + b)*NSP + n)*2 + 1];
    }
    float M = fmaxf(fmaxf(mv[0],mv[1]), fmaxf(mv[2],mv[3]));
    float wsum = 0.f, wv[SPLITS];
    #pragma unroll
    for (int s=0;s<SPLITS;++s){ wv[s] = lv[s]*exp2f(mv[s]-M); wsum += wv[s]; }
    float inv = 1.f/wsum;
    #pragma unroll
    for (int s=0;s<SPLITS;++s) wc[s][r] = wv[s]*inv;
  }
  __syncthreads();
  // combine ypart -> ys (once)
  #pragma unroll
  for (int p=0;p<4;++p){
    int id = p*256 + t, r = id>>4, c8 = (id&15)*8;
    float accv[8] = {0,0,0,0,0,0,0,0};
    #pragma unroll
    for (int s=0;s<SPLITS;++s){
      short8 v = *(const short8*)(ypart + (((size_t)s*4 + b)*NSP + n0 + r)*ICH + c8);
      float wgt = wc[s][r];
      #pragma unroll
      for (int i=0;i<8;++i) accv[i] += wgt * h2f(((unsigned short*)&v)[i]);
    }
    unsigned short hv[8];
    #pragma unroll
    for (int i=0;i<8;++i) hv[i] = f2h(accv[i]);
    *(short8*)&ys[r][swz(r,c8)] = *(short8*)hv;
  }

  const f32x4 Z = {0.f,0.f,0.f,0.f};
  #pragma unroll
  for (int ot2 = 0; ot2 < 2; ++ot2){
    const int o0 = obase + ot2*64;
    #pragma unroll
    for (int p=0;p<4;++p){
      int id = p*256 + t, r = id>>4, c8 = (id&15)*8;
      float4 u0 = *(const float4*)(Wm + (size_t)(o0 + r)*ICH + c8);
      float4 u1 = *(const float4*)(Wm + (size_t)(o0 + r)*ICH + c8 + 4);
      unsigned short wh[8] = {f2h(u0.x),f2h(u0.y),f2h(u0.z),f2h(u0.w),
                              f2h(u1.x),f2h(u1.y),f2h(u1.z),f2h(u1.w)};
      *(short8*)&w2s[r][swz(r,c8)] = *(short8*)wh;
    }
    __syncthreads();
    f32x4 acc[4];
    #pragma unroll
    for (int i=0;i<4;++i) acc[i]=Z;
    #pragma unroll
    for (int kf=0;kf<4;++kf){
      int ko = kf*32 + (l>>4)*8;
      int wr = 16*w + (l&15);
      short8 a = *(const short8*)&w2s[wr][swz(wr,ko)];
      #pragma unroll
      for (int nf=0;nf<4;++nf){
        int yr = 16*nf + (l&15);
        short8 bb = *(const short8*)&ys[yr][swz(yr,ko)];
        acc[nf] = mfmah(a, bb, acc[nf]);
      }
    }
    #pragma unroll
    for (int j=0;j<4;++j){
      int ol = 16*w + (l>>4)*4 + j;
      float s = sc_s[ot2*64 + ol], sh = sh_s[ot2*64 + ol];
      #pragma unroll
      for (int nf=0;nf<4;++nf){
        int n = n0 + 16*nf + (l&15);
        size_t idx = ((size_t)b*CIN + o0 + ol)*NSP + n;
        out[idx] = acc[nf][j]*s + sh + x[idx];
      }
    }
    __syncthreads();
  }
}

extern "C" void kernel_launch(void* const* d_in, const int* in_sizes, int n_in,
                              void* d_out, int out_size, void* d_ws, size_t ws_size,
                              hipStream_t stream){
  const float* x    = (const float*)d_in[0];
  const float* g_w  = (const float*)d_in[1];
  const float* g_b  = (const float*)d_in[2];
  const float* g_ga = (const float*)d_in[3];
  const float* g_be = (const float*)d_in[4];
  const float* g_me = (const float*)d_in[5];
  const float* g_va = (const float*)d_in[6];
  const float* t_w  = (const float*)d_in[7];
  const float* t_b  = (const float*)d_in[8];
  const float* t_ga = (const float*)d_in[9];
  const float* t_be = (const float*)d_in[10];
  const float* t_me = (const float*)d_in[11];
  const float* t_va = (const float*)d_in[12];
  const float* p_w  = (const float*)d_in[13];
  const float* p_b  = (const float*)d_in[14];
  const float* p_ga = (const float*)d_in[15];
  const float* p_be = (const float*)d_in[16];
  const float* p_me = (const float*)d_in[17];
  const float* p_va = (const float*)d_in[18];
  const float* w_w  = (const float*)d_in[19];
  const float* w_b  = (const float*)d_in[20];
  const float* w_ga = (const float*)d_in[21];
  const float* w_be = (const float*)d_in[22];
  const float* w_me = (const float*)d_in[23];
  const float* w_va = (const float*)d_in[24];

  char* ws = (char*)d_ws;
  const size_t SEG = (size_t)4*NSP*ICH*sizeof(unsigned short);   // 4 MB
  unsigned short* th_t  = (unsigned short*)(ws);
  unsigned short* ph_t  = (unsigned short*)(ws + SEG);
  unsigned short* g_cn  = (unsigned short*)(ws + 2*SEG);
  unsigned short* ypart = (unsigned short*)(ws + 3*SEG);
  float*          mlb   = (float*)(ws + 3*SEG + SPLITS*SEG);

  dim3 blk(256,1,1);
  conv_fused_k<<<dim3(64,2,4), blk, 0, stream>>>(
      x,
      g_w, g_b, g_ga, g_be, g_me, g_va,
      t_w, t_b, t_ga, t_be, t_me, t_va,
      p_w, p_b, p_ga, p_be, p_me, p_va,
      g_cn, th_t, ph_t);
  attn_k<<<dim3(512,1,1), blk, 0, stream>>>(th_t, ph_t, g_cn, ypart, mlb);
  final_k2<<<dim3(64,2,4), blk, 0, stream>>>(ypart, mlb, x, w_w, w_b, w_ga, w_be, w_me, w_va, (float*)d_out);
}

// Round 21
// 68.770 us; speedup vs baseline: 1.7434x; 1.0085x over previous
//
#include <hip/hip_runtime.h>
#include <math.h>

typedef __attribute__((ext_vector_type(8))) short short8;
typedef __attribute__((ext_vector_type(8))) _Float16 half8;
typedef __attribute__((ext_vector_type(4))) float f32x4;
typedef __attribute__((ext_vector_type(16))) float f32x16;

#define NSP 4096
#define CIN 256
#define ICH 128
#define SPLITS 4
#define TILES_PER_SPLIT 16
#define LOG2E 1.44269504088896f

__device__ __forceinline__ unsigned short f2h(float x){
  union { _Float16 h; unsigned short u; } v; v.h = (_Float16)x; return v.u;
}
__device__ __forceinline__ float h2f(unsigned short u){
  union { _Float16 h; unsigned short u; } v; v.u = u; return (float)v.h;
}
// pack two f32 -> two f16 in one u32 (v_cvt_pkrtz_f16_f32)
__device__ __forceinline__ unsigned pk2h(float a, float b){
  union { __fp16 __attribute__((ext_vector_type(2))) v; unsigned u; } r;
  r.v = __builtin_amdgcn_cvt_pkrtz(a, b);
  return r.u;
}
// raw 2^x via v_exp_f32
__device__ __forceinline__ float fexp2(float x){
  float r;
  asm("v_exp_f32 %0, %1" : "=v"(r) : "v"(x));
  return r;
}
// LDS swizzles (element units; 8-chunk preserving)
__device__ __forceinline__ int swz(int row, int e){ return e ^ ((row & 7) << 3); }    // 64-elem rows
__device__ __forceinline__ int swzK(int row, int e){ return e ^ ((row & 15) << 3); }  // 128-elem rows

__device__ __forceinline__ f32x4 mfmah(short8 a, short8 b, f32x4 c){
  union { short8 s; half8 h; } ua, ub; ua.s = a; ub.s = b;
  return __builtin_amdgcn_mfma_f32_16x16x32_f16(ua.h, ub.h, c, 0, 0, 0);
}
__device__ __forceinline__ f32x16 mfma32(short8 a, short8 b, f32x16 c){
  union { short8 s; half8 h; } ua, ub; ua.s = a; ub.s = b;
  return __builtin_amdgcn_mfma_f32_32x32x16_f16(ua.h, ub.h, c, 0, 0, 0);
}

// async global->LDS, 16B per lane. LDS dest = wave-uniform base + lane*16 (linear).
__device__ __forceinline__ void gload_lds16(const unsigned short* g, unsigned short* l){
  __builtin_amdgcn_global_load_lds(
      (const __attribute__((address_space(1))) unsigned int*)g,
      (__attribute__((address_space(3))) unsigned int*)l, 16, 0, 0);
}

// Stage a 64x128 fp16 tile into LDS flat [64][128], swzK pre-applied on SOURCE.
__device__ __forceinline__ void stage_nc(const unsigned short* gbase, unsigned short* lds,
                                         int w, int l){
  #pragma unroll
  for (int i=0;i<4;++i){
    int rl = 16*w + 4*i + (l>>4);
    int eg = ((l&15)*8) ^ ((rl&15)<<3);
    gload_lds16(gbase + (size_t)rl*128 + eg, lds + w*2048 + i*512);
  }
}

// k-order permutation for PV with 32x32x16 A-fragments (see R16 derivation)
__device__ __forceinline__ int kperm(int q){
  int m = q & 15;
  return (q & 16) | (((m>>2)&1)<<3) | (m&3) | (((m>>3)&1)<<2);
}

// ---------------------------------------------------------------------------
// Fused 3-branch conv+BN+ReLU with T14 async-stage split: next chunk's x/W
// global loads are issued under the current chunk's MFMA phase (latency
// hidden). Staging uses packed cvt_pkrtz + b32/b64 LDS stores.
// g written kperm-permuted; theta pre-scaled by log2(e).
// ---------------------------------------------------------------------------
__global__ __launch_bounds__(256) void conv_fused_k(
    const float* __restrict__ x,
    const float* __restrict__ w0, const float* __restrict__ b0,
    const float* __restrict__ ga0, const float* __restrict__ be0,
    const float* __restrict__ me0, const float* __restrict__ va0,
    const float* __restrict__ w1, const float* __restrict__ b1,
    const float* __restrict__ ga1, const float* __restrict__ be1,
    const float* __restrict__ me1, const float* __restrict__ va1,
    const float* __restrict__ w2, const float* __restrict__ b2,
    const float* __restrict__ ga2, const float* __restrict__ be2,
    const float* __restrict__ me2, const float* __restrict__ va2,
    unsigned short* __restrict__ outg, unsigned short* __restrict__ outt,
    unsigned short* __restrict__ outp)
{
  const int b = blockIdx.z, nt = blockIdx.x, ot = blockIdx.y;
  const int n0 = nt*64, o0 = ot*64;
  const int t = threadIdx.x, w = t>>6, l = t&63;
  __shared__ unsigned short xs[64][64];
  __shared__ unsigned short ws[3][64][64];
  __shared__ float sc_s[3][64], sh_s[3][64];
  if (t < 64){
    int o = o0 + t;
    float s0 = ga0[o]*rsqrtf(va0[o]+1e-5f);
    sc_s[0][t]=s0; sh_s[0][t]=be0[o]-me0[o]*s0+b0[o]*s0;
    float s1 = ga1[o]*rsqrtf(va1[o]+1e-5f);
    sc_s[1][t]=s1*LOG2E; sh_s[1][t]=(be1[o]-me1[o]*s1+b1[o]*s1)*LOG2E;
    float s2 = ga2[o]*rsqrtf(va2[o]+1e-5f);
    sc_s[2][t]=s2; sh_s[2][t]=be2[o]-me2[o]*s2+b2[o]*s2;
  }
  const f32x4 Z = {0.f,0.f,0.f,0.f};
  f32x4 acc[3][4];
  #pragma unroll
  for (int br=0;br<3;++br) for (int i=0;i<4;++i) acc[br][i] = Z;
  const float* Wt[3] = {w0, w1, w2};

  // prefetch registers for one k-chunk
  float4 xg0[2], xg1[2];      // [p2]: row cpr and cpr+1
  float4 wg[4][3];            // [p][br]
  const int cbase = 2*(t>>4);
  const int nb = (t&15)*4;
  const int q4 = (t&15)*4;

  // preload chunk 0
  #pragma unroll
  for (int p2=0;p2<2;++p2){
    const float* xr0 = x + ((size_t)b*CIN + p2*32 + cbase)*NSP + n0 + nb;
    xg0[p2] = *(const float4*)xr0;
    xg1[p2] = *(const float4*)(xr0 + NSP);
  }
  #pragma unroll
  for (int p=0;p<4;++p){
    int cw = p*16 + (t>>4);
    #pragma unroll
    for (int br=0;br<3;++br)
      wg[p][br] = *(const float4*)(Wt[br] + (size_t)(o0 + cw)*CIN + q4);
  }

  #pragma unroll
  for (int ci = 0; ci < 4; ++ci){
    __syncthreads();   // prior MFMA reads of LDS done
    // store prefetched regs -> LDS (packed cvt)
    #pragma unroll
    for (int p2=0;p2<2;++p2){
      int cpr = p2*32 + cbase;
      float aa[4] = {xg0[p2].x, xg0[p2].y, xg0[p2].z, xg0[p2].w};
      float bb[4] = {xg1[p2].x, xg1[p2].y, xg1[p2].z, xg1[p2].w};
      #pragma unroll
      for (int i=0;i<4;++i){
        int r = nb + i;
        *(unsigned*)&xs[r][swz(r, cpr)] = pk2h(aa[i], bb[i]);
      }
    }
    #pragma unroll
    for (int p=0;p<4;++p){
      int cw = p*16 + (t>>4);
      #pragma unroll
      for (int br=0;br<3;++br){
        float4 wv = wg[p][br];
        uint2 u; u.x = pk2h(wv.x, wv.y); u.y = pk2h(wv.z, wv.w);
        *(uint2*)&ws[br][cw][swz(cw, q4)] = u;
      }
    }
    // issue next chunk's loads (latency hidden under MFMA below)
    if (ci < 3){
      int kc = (ci+1)*64;
      #pragma unroll
      for (int p2=0;p2<2;++p2){
        const float* xr0 = x + ((size_t)b*CIN + kc + p2*32 + cbase)*NSP + n0 + nb;
        xg0[p2] = *(const float4*)xr0;
        xg1[p2] = *(const float4*)(xr0 + NSP);
      }
      #pragma unroll
      for (int p=0;p<4;++p){
        int cw = p*16 + (t>>4);
        #pragma unroll
        for (int br=0;br<3;++br)
          wg[p][br] = *(const float4*)(Wt[br] + (size_t)(o0 + cw)*CIN + kc + q4);
      }
    }
    __syncthreads();   // stores visible
    #pragma unroll
    for (int kf = 0; kf < 2; ++kf){
      int ko = kf*32 + (l>>4)*8;
      int wr = 16*w + (l&15);
      short8 wf0 = *(const short8*)&ws[0][wr][swz(wr, ko)];
      short8 wf1 = *(const short8*)&ws[1][wr][swz(wr, ko)];
      short8 wf2 = *(const short8*)&ws[2][wr][swz(wr, ko)];
      #pragma unroll
      for (int nf = 0; nf < 4; ++nf){
        int xr = 16*nf + (l&15);
        short8 xf = *(const short8*)&xs[xr][swz(xr, ko)];
        acc[0][nf] = mfmah(wf0, xf, acc[0][nf]);   // orient0 (g)
        acc[1][nf] = mfmah(xf, wf1, acc[1][nf]);   // orient1 (theta)
        acc[2][nf] = mfmah(xf, wf2, acc[2][nf]);   // orient1 (phi)
      }
    }
  }
  // g epilogue (orient0, kperm-permuted column order)
  #pragma unroll
  for (int j=0;j<4;++j){
    int ol = 16*w + (l>>4)*4 + j;
    float s = sc_s[0][ol], sh = sh_s[0][ol];
    #pragma unroll
    for (int nf=0;nf<4;++nf){
      int n = n0 + 16*nf + (l&15);
      int nst = (n & ~31) | kperm(n & 31);
      float v = fmaxf(acc[0][nf][j]*s + sh, 0.f);
      outg[((size_t)b*ICH + o0 + ol)*NSP + nst] = f2h(v);
    }
  }
  // theta/phi epilogue (orient1)
  {
    int ol = 16*w + (l&15);
    float s1 = sc_s[1][ol], sh1 = sh_s[1][ol];
    float s2 = sc_s[2][ol], sh2 = sh_s[2][ol];
    #pragma unroll
    for (int nf=0; nf<4; ++nf)
      #pragma unroll
      for (int j=0;j<4;++j){
        int n = n0 + 16*nf + (l>>4)*4 + j;
        float v1 = fmaxf(acc[1][nf][j]*s1 + sh1, 0.f);
        float v2 = fmaxf(acc[2][nf][j]*s2 + sh2, 0.f);
        outt[((size_t)b*NSP + n)*ICH + o0 + ol] = f2h(v1);
        outp[((size_t)b*NSP + n)*ICH + o0 + ol] = f2h(v2);
      }
  }
}

// ---------------------------------------------------------------------------
// Flash attention, 32x32x16 MFMA, 4 waves x 32 Q rows. Softmax/PV interleaved:
// exp(sc0)+pack -> PV-a, exp(sc1)+pack -> PV-b (trans pipe overlaps matrix).
// ---------------------------------------------------------------------------
__global__ __launch_bounds__(256, 2) void attn_k(
  const unsigned short* __restrict__ thp, const unsigned short* __restrict__ php,
  const unsigned short* __restrict__ gb, unsigned short* __restrict__ ypart,
  float* __restrict__ ml)
{
  const int bx = blockIdx.x;
  const int xcd = bx & 7, jj = bx >> 3;
  const int combo = xcd*2 + (jj>>5);
  const int qt = jj & 31;
  const int b = combo & 3, s = combo >> 2;
  const int n0 = qt*128;
  const int t = threadIdx.x, w = t>>6, l = t&63;
  const int hi = l>>5, ln = l&31;

  __shared__ unsigned short kb[2][8192];   // K double buffer [64][128]
  __shared__ unsigned short vb[2][8192];   // V double buffer [128][64]

  // ---- stage Q halves through kb[0]/kb[1], preload 8 B-fragments ----
  stage_nc(thp + ((size_t)b*NSP + n0      )*ICH, &kb[0][0], w, l);
  stage_nc(thp + ((size_t)b*NSP + n0 + 64 )*ICH, &kb[1][0], w, l);
  __syncthreads();
  short8 qf[8];
  {
    const unsigned short* qsrc = (w >> 1) ? &kb[1][0] : &kb[0][0];
    int r = 32*(w & 1) + ln;
    #pragma unroll
    for (int kc=0;kc<8;++kc)
      qf[kc] = *(const short8*)&qsrc[r*128 + swzK(r, kc*16 + 8*hi)];
  }
  __syncthreads();

  f32x16 oa[4];
  #pragma unroll
  for (int i=0;i<4;++i)
    #pragma unroll
    for (int j=0;j<16;++j) oa[i][j] = 0.f;
  float mr = -1e30f, lr = 0.f;
  unsigned pk[16];

  const int tile0 = s*TILES_PER_SPLIT;

  // ---- hoisted per-lane staging pointers ----
  const unsigned short* kp[4];
  const unsigned short* vp[4];
  {
    const unsigned short* kbase = php + ((size_t)b*NSP + tile0*64)*ICH;
    const unsigned short* vbase = gb + (size_t)b*ICH*NSP + tile0*64;
    #pragma unroll
    for (int i=0;i<4;++i){
      int rl = 16*w + 4*i + (l>>4);
      int eg = ((l&15)*8) ^ ((rl&15)<<3);
      kp[i] = kbase + (size_t)rl*128 + eg;
      int cl = 32*w + 8*i + (l>>3);
      int me = ((l&7)*8) ^ ((cl&7)<<3);
      vp[i] = vbase + (size_t)cl*NSP + me;
    }
  }
  // prologue: stage tile0 into buffer 0
  {
    unsigned short* kd = &kb[0][0] + w*2048;
    unsigned short* vd = &vb[0][0] + w*2048;
    #pragma unroll
    for (int i=0;i<4;++i){
      gload_lds16(kp[i], kd + i*512); kp[i] += 64*ICH;
      gload_lds16(vp[i], vd + i*512); vp[i] += 64;
    }
  }
  __syncthreads();
  int cur = 0;

  for (int it = 0; it < TILES_PER_SPLIT; ++it){
    // (A) prefetch next K+V
    if (it < TILES_PER_SPLIT-1){
      unsigned short* kd = &kb[cur^1][0] + w*2048;
      unsigned short* vd = &vb[cur^1][0] + w*2048;
      #pragma unroll
      for (int i=0;i<4;++i){
        gload_lds16(kp[i], kd + i*512); kp[i] += 64*ICH;
        gload_lds16(vp[i], vd + i*512); vp[i] += 64;
      }
    }

    // (B) swapped QK^T: sc rows = m, cols = n. 16 mfma_32x32x16.
    f32x16 sc0, sc1;
    #pragma unroll
    for (int j=0;j<16;++j){ sc0[j]=0.f; sc1[j]=0.f; }
    __builtin_amdgcn_s_setprio(1);
    #pragma unroll
    for (int kc=0;kc<8;++kc){
      int eo = kc*16 + 8*hi;
      short8 a0 = *(const short8*)&kb[cur][(ln     )*128 + swzK(ln,      eo)];
      short8 a1 = *(const short8*)&kb[cur][(32 + ln)*128 + swzK(32 + ln, eo)];
      sc0 = mfma32(a0, qf[kc], sc0);
      sc1 = mfma32(a1, qf[kc], sc1);
    }
    __builtin_amdgcn_s_setprio(0);

    // (C1) max reduce + deferred rescale
    {
      float t0 = fmaxf(fmaxf(sc0[0],sc0[1]),  fmaxf(sc0[2],sc0[3]));
      float t1 = fmaxf(fmaxf(sc0[4],sc0[5]),  fmaxf(sc0[6],sc0[7]));
      float t2 = fmaxf(fmaxf(sc0[8],sc0[9]),  fmaxf(sc0[10],sc0[11]));
      float t3 = fmaxf(fmaxf(sc0[12],sc0[13]),fmaxf(sc0[14],sc0[15]));
      float t4 = fmaxf(fmaxf(sc1[0],sc1[1]),  fmaxf(sc1[2],sc1[3]));
      float t5 = fmaxf(fmaxf(sc1[4],sc1[5]),  fmaxf(sc1[6],sc1[7]));
      float t6 = fmaxf(fmaxf(sc1[8],sc1[9]),  fmaxf(sc1[10],sc1[11]));
      float t7 = fmaxf(fmaxf(sc1[12],sc1[13]),fmaxf(sc1[14],sc1[15]));
      float mx = fmaxf(fmaxf(fmaxf(t0,t1),fmaxf(t2,t3)),
                       fmaxf(fmaxf(t4,t5),fmaxf(t6,t7)));
      mx = fmaxf(mx, __shfl_xor(mx, 32));
      if (__any(mx - mr > 11.5f)){   // defer-max (log2 units)
        float mn = fmaxf(mr, mx);
        float al = fexp2(mr - mn);
        mr = mn; lr *= al;
        #pragma unroll
        for (int j=0;j<16;++j){
          int rowj = (j&3) + 8*(j>>2) + 4*hi;
          float alj = __shfl(al, rowj);
          #pragma unroll
          for (int ct=0;ct<4;++ct) oa[ct][j] *= alj;
        }
      }
    }

    float sA=0.f, sB=0.f, sC=0.f, sD=0.f;
    // (C2a) exp sc0 + pack pk[0..7]
    #pragma unroll
    for (int r=0;r<16;r+=4){
      sc0[r]   = fexp2(sc0[r]  -mr); sA += sc0[r];
      sc0[r+1] = fexp2(sc0[r+1]-mr); sB += sc0[r+1];
      sc0[r+2] = fexp2(sc0[r+2]-mr); sC += sc0[r+2];
      sc0[r+3] = fexp2(sc0[r+3]-mr); sD += sc0[r+3];
    }
    #pragma unroll
    for (int s2=0;s2<2;++s2)
      #pragma unroll
      for (int q=0;q<4;++q)
        pk[s2*4+q] = pk2h(sc0[8*s2+2*q], sc0[8*s2+2*q+1]);
    // (D-a) PV for sc0's m-rows (overlappable with C2b below)
    __builtin_amdgcn_s_setprio(1);
    #pragma unroll
    for (int s2=0;s2<2;++s2){
      union { unsigned u[4]; short8 s8; } au;
      #pragma unroll
      for (int q=0;q<4;++q) au.u[q] = pk[4*s2+q];
      int eo = 16*s2 + 8*hi;
      #pragma unroll
      for (int ct=0;ct<4;++ct){
        int cr = 32*ct + ln;
        short8 bv = *(const short8*)&vb[cur][cr*64 + swz(cr, eo)];
        oa[ct] = mfma32(au.s8, bv, oa[ct]);
      }
    }
    __builtin_amdgcn_s_setprio(0);
    // (C2b) exp sc1 + pack pk[8..15]
    #pragma unroll
    for (int r=0;r<16;r+=4){
      sc1[r]   = fexp2(sc1[r]  -mr); sA += sc1[r];
      sc1[r+1] = fexp2(sc1[r+1]-mr); sB += sc1[r+1];
      sc1[r+2] = fexp2(sc1[r+2]-mr); sC += sc1[r+2];
      sc1[r+3] = fexp2(sc1[r+3]-mr); sD += sc1[r+3];
    }
    #pragma unroll
    for (int s2=0;s2<2;++s2)
      #pragma unroll
      for (int q=0;q<4;++q)
        pk[8+s2*4+q] = pk2h(sc1[8*s2+2*q], sc1[8*s2+2*q+1]);
    lr += (sA + sB) + (sC + sD);
    // (D-b) PV for sc1's m-rows
    __builtin_amdgcn_s_setprio(1);
    #pragma unroll
    for (int s2=0;s2<2;++s2){
      union { unsigned u[4]; short8 s8; } au;
      #pragma unroll
      for (int q=0;q<4;++q) au.u[q] = pk[8+4*s2+q];
      int eo = 32 + 16*s2 + 8*hi;
      #pragma unroll
      for (int ct=0;ct<4;++ct){
        int cr = 32*ct + ln;
        short8 bv = *(const short8*)&vb[cur][cr*64 + swz(cr, eo)];
        oa[ct] = mfma32(au.s8, bv, oa[ct]);
      }
    }
    __builtin_amdgcn_s_setprio(0);

    __syncthreads();
    cur ^= 1;
  }

  // ---- epilogue: combine partner sums, normalize, write ----
  lr += __shfl_xor(lr, 32);
  float invl = 1.f / lr;
  #pragma unroll
  for (int j=0;j<16;++j){
    int rowj = (j&3) + 8*(j>>2) + 4*hi;
    float invj = __shfl(invl, rowj);
    int n = n0 + 32*w + rowj;
    #pragma unroll
    for (int ct=0;ct<4;++ct){
      int c = 32*ct + ln;
      ypart[(((size_t)s*4 + b)*NSP + n)*ICH + c] = f2h(oa[ct][j]*invj);
    }
  }
  if (l < 32){
    int n = n0 + 32*w + l;
    ml[(((size_t)s*4 + b)*NSP + n)*2 + 0] = mr;
    ml[(((size_t)s*4 + b)*NSP + n)*2 + 1] = lr;
  }
}

// ---------------------------------------------------------------------------
// Final conv + fused split-combine, 2 o-tiles per block; packed W2 staging.
// ---------------------------------------------------------------------------
__global__ __launch_bounds__(256) void final_k2(
  const unsigned short* __restrict__ ypart, const float* __restrict__ ml,
  const float* __restrict__ x, const float* __restrict__ Wm,
  const float* __restrict__ bias, const float* __restrict__ gamma,
  const float* __restrict__ beta, const float* __restrict__ mean,
  const float* __restrict__ var, float* __restrict__ out)
{
  const int b = blockIdx.z, oth = blockIdx.y, nt = blockIdx.x;
  const int n0 = nt*64, obase = oth*128;
  const int t = threadIdx.x, w = t>>6, l = t&63;
  __shared__ unsigned short ys[64][128];
  __shared__ unsigned short w2s[64][128];
  __shared__ float wc[SPLITS][64];
  __shared__ float sc_s[128], sh_s[128];
  if (t < 128){
    int o = obase + t;
    float s = gamma[o]*rsqrtf(var[o]+1e-5f);
    sc_s[t]=s; sh_s[t]=beta[o]-mean[o]*s+bias[o]*s;
  } else if (t < 192){
    int r = t - 128, n = n0 + r;
    float mv[SPLITS], lv[SPLITS];
    #pragma unroll
    for (int s=0;s<SPLITS;++s){
      mv[s] = ml[(((size_t)s*4 + b)*NSP + n)*2 + 0];
      lv[s] = ml[(((size_t)s*4 + b)*NSP + n)*2 + 1];
    }
    float M = fmaxf(fmaxf(mv[0],mv[1]), fmaxf(mv[2],mv[3]));
    float wsum = 0.f, wv[SPLITS];
    #pragma unroll
    for (int s=0;s<SPLITS;++s){ wv[s] = lv[s]*exp2f(mv[s]-M); wsum += wv[s]; }
    float inv = 1.f/wsum;
    #pragma unroll
    for (int s=0;s<SPLITS;++s) wc[s][r] = wv[s]*inv;
  }
  __syncthreads();
  // combine ypart -> ys (once)
  #pragma unroll
  for (int p=0;p<4;++p){
    int id = p*256 + t, r = id>>4, c8 = (id&15)*8;
    float accv[8] = {0,0,0,0,0,0,0,0};
    #pragma unroll
    for (int s=0;s<SPLITS;++s){
      short8 v = *(const short8*)(ypart + (((size_t)s*4 + b)*NSP + n0 + r)*ICH + c8);
      float wgt = wc[s][r];
      #pragma unroll
      for (int i=0;i<8;++i) accv[i] += wgt * h2f(((unsigned short*)&v)[i]);
    }
    uint2 hv;
    hv.x = pk2h(accv[0], accv[1]);
    hv.y = pk2h(accv[2], accv[3]);
    uint2 hv2;
    hv2.x = pk2h(accv[4], accv[5]);
    hv2.y = pk2h(accv[6], accv[7]);
    *(uint2*)&ys[r][swz(r,c8)] = hv;
    *(uint2*)&ys[r][swz(r,c8)+4] = hv2;
  }

  const f32x4 Z = {0.f,0.f,0.f,0.f};
  #pragma unroll
  for (int ot2 = 0; ot2 < 2; ++ot2){
    const int o0 = obase + ot2*64;
    #pragma unroll
    for (int p=0;p<4;++p){
      int id = p*256 + t, r = id>>4, c8 = (id&15)*8;
      float4 u0 = *(const float4*)(Wm + (size_t)(o0 + r)*ICH + c8);
      float4 u1 = *(const float4*)(Wm + (size_t)(o0 + r)*ICH + c8 + 4);
      uint2 u; u.x = pk2h(u0.x, u0.y); u.y = pk2h(u0.z, u0.w);
      uint2 v2; v2.x = pk2h(u1.x, u1.y); v2.y = pk2h(u1.z, u1.w);
      *(uint2*)&w2s[r][swz(r,c8)] = u;
      *(uint2*)&w2s[r][swz(r,c8)+4] = v2;
    }
    __syncthreads();
    f32x4 acc[4];
    #pragma unroll
    for (int i=0;i<4;++i) acc[i]=Z;
    #pragma unroll
    for (int kf=0;kf<4;++kf){
      int ko = kf*32 + (l>>4)*8;
      int wr = 16*w + (l&15);
      short8 a = *(const short8*)&w2s[wr][swz(wr,ko)];
      #pragma unroll
      for (int nf=0;nf<4;++nf){
        int yr = 16*nf + (l&15);
        short8 bb = *(const short8*)&ys[yr][swz(yr,ko)];
        acc[nf] = mfmah(a, bb, acc[nf]);
      }
    }
    #pragma unroll
    for (int j=0;j<4;++j){
      int ol = 16*w + (l>>4)*4 + j;
      float s = sc_s[ot2*64 + ol], sh = sh_s[ot2*64 + ol];
      #pragma unroll
      for (int nf=0;nf<4;++nf){
        int n = n0 + 16*nf + (l&15);
        size_t idx = ((size_t)b*CIN + o0 + ol)*NSP + n;
        out[idx] = acc[nf][j]*s + sh + x[idx];
      }
    }
    __syncthreads();
  }
}

extern "C" void kernel_launch(void* const* d_in, const int* in_sizes, int n_in,
                              void* d_out, int out_size, void* d_ws, size_t ws_size,
                              hipStream_t stream){
  const float* x    = (const float*)d_in[0];
  const float* g_w  = (const float*)d_in[1];
  const float* g_b  = (const float*)d_in[2];
  const float* g_ga = (const float*)d_in[3];
  const float* g_be = (const float*)d_in[4];
  const float* g_me = (const float*)d_in[5];
  const float* g_va = (const float*)d_in[6];
  const float* t_w  = (const float*)d_in[7];
  const float* t_b  = (const float*)d_in[8];
  const float* t_ga = (const float*)d_in[9];
  const float* t_be = (const float*)d_in[10];
  const float* t_me = (const float*)d_in[11];
  const float* t_va = (const float*)d_in[12];
  const float* p_w  = (const float*)d_in[13];
  const float* p_b  = (const float*)d_in[14];
  const float* p_ga = (const float*)d_in[15];
  const float* p_be = (const float*)d_in[16];
  const float* p_me = (const float*)d_in[17];
  const float* p_va = (const float*)d_in[18];
  const float* w_w  = (const float*)d_in[19];
  const float* w_b  = (const float*)d_in[20];
  const float* w_ga = (const float*)d_in[21];
  const float* w_be = (const float*)d_in[22];
  const float* w_me = (const float*)d_in[23];
  const float* w_va = (const float*)d_in[24];

  char* ws = (char*)d_ws;
  const size_t SEG = (size_t)4*NSP*ICH*sizeof(unsigned short);   // 4 MB
  unsigned short* th_t  = (unsigned short*)(ws);
  unsigned short* ph_t  = (unsigned short*)(ws + SEG);
  unsigned short* g_cn  = (unsigned short*)(ws + 2*SEG);
  unsigned short* ypart = (unsigned short*)(ws + 3*SEG);
  float*          mlb   = (float*)(ws + 3*SEG + SPLITS*SEG);

  dim3 blk(256,1,1);
  conv_fused_k<<<dim3(64,2,4), blk, 0, stream>>>(
      x,
      g_w, g_b, g_ga, g_be, g_me, g_va,
      t_w, t_b, t_ga, t_be, t_me, t_va,
      p_w, p_b, p_ga, p_be, p_me, p_va,
      g_cn, th_t, ph_t);
  attn_k<<<dim3(512,1,1), blk, 0, stream>>>(th_t, ph_t, g_cn, ypart, mlb);
  final_k2<<<dim3(64,2,4), blk, 0, stream>>>(ypart, mlb, x, w_w, w_b, w_ga, w_be, w_me, w_va, (float*)d_out);
}

// Round 22
// 68.626 us; speedup vs baseline: 1.7470x; 1.0021x over previous
//
#include <hip/hip_runtime.h>
#include <math.h>

typedef __attribute__((ext_vector_type(8))) short short8;
typedef __attribute__((ext_vector_type(8))) _Float16 half8;
typedef __attribute__((ext_vector_type(4))) float f32x4;
typedef __attribute__((ext_vector_type(16))) float f32x16;

#define NSP 4096
#define CIN 256
#define ICH 128
#define SPLITS 4
#define TILES_PER_SPLIT 16
#define LOG2E 1.44269504088896f

__device__ __forceinline__ unsigned short f2h(float x){
  union { _Float16 h; unsigned short u; } v; v.h = (_Float16)x; return v.u;
}
__device__ __forceinline__ float h2f(unsigned short u){
  union { _Float16 h; unsigned short u; } v; v.u = u; return (float)v.h;
}
// pack two f32 -> two f16 in one u32 (v_cvt_pkrtz_f16_f32)
__device__ __forceinline__ unsigned pk2h(float a, float b){
  union { __fp16 __attribute__((ext_vector_type(2))) v; unsigned u; } r;
  r.v = __builtin_amdgcn_cvt_pkrtz(a, b);
  return r.u;
}
// raw 2^x via v_exp_f32
__device__ __forceinline__ float fexp2(float x){
  float r;
  asm("v_exp_f32 %0, %1" : "=v"(r) : "v"(x));
  return r;
}
// LDS swizzles (element units; 8-chunk preserving)
__device__ __forceinline__ int swz(int row, int e){ return e ^ ((row & 7) << 3); }    // 64-elem rows
__device__ __forceinline__ int swzK(int row, int e){ return e ^ ((row & 15) << 3); }  // 128-elem rows

__device__ __forceinline__ f32x4 mfmah(short8 a, short8 b, f32x4 c){
  union { short8 s; half8 h; } ua, ub; ua.s = a; ub.s = b;
  return __builtin_amdgcn_mfma_f32_16x16x32_f16(ua.h, ub.h, c, 0, 0, 0);
}
__device__ __forceinline__ f32x16 mfma32(short8 a, short8 b, f32x16 c){
  union { short8 s; half8 h; } ua, ub; ua.s = a; ub.s = b;
  return __builtin_amdgcn_mfma_f32_32x32x16_f16(ua.h, ub.h, c, 0, 0, 0);
}

// async global->LDS, 16B per lane. LDS dest = wave-uniform base + lane*16 (linear).
__device__ __forceinline__ void gload_lds16(const unsigned short* g, unsigned short* l){
  __builtin_amdgcn_global_load_lds(
      (const __attribute__((address_space(1))) unsigned int*)g,
      (__attribute__((address_space(3))) unsigned int*)l, 16, 0, 0);
}

// Stage a 64x128 fp16 tile into LDS flat [64][128], swzK pre-applied on SOURCE.
__device__ __forceinline__ void stage_nc(const unsigned short* gbase, unsigned short* lds,
                                         int w, int l){
  #pragma unroll
  for (int i=0;i<4;++i){
    int rl = 16*w + 4*i + (l>>4);
    int eg = ((l&15)*8) ^ ((rl&15)<<3);
    gload_lds16(gbase + (size_t)rl*128 + eg, lds + w*2048 + i*512);
  }
}

// k-order permutation for PV with 32x32x16 A-fragments (see R16 derivation)
__device__ __forceinline__ int kperm(int q){
  int m = q & 15;
  return (q & 16) | (((m>>2)&1)<<3) | (m&3) | (((m>>3)&1)<<2);
}

// ---------------------------------------------------------------------------
// Fused 3-branch conv+BN+ReLU with T14 async-stage split: next chunk's x/W
// global loads are issued under the current chunk's MFMA phase (latency
// hidden). Staging uses packed cvt_pkrtz + b32/b64 LDS stores.
// g written kperm-permuted; theta pre-scaled by log2(e).
// ---------------------------------------------------------------------------
__global__ __launch_bounds__(256) void conv_fused_k(
    const float* __restrict__ x,
    const float* __restrict__ w0, const float* __restrict__ b0,
    const float* __restrict__ ga0, const float* __restrict__ be0,
    const float* __restrict__ me0, const float* __restrict__ va0,
    const float* __restrict__ w1, const float* __restrict__ b1,
    const float* __restrict__ ga1, const float* __restrict__ be1,
    const float* __restrict__ me1, const float* __restrict__ va1,
    const float* __restrict__ w2, const float* __restrict__ b2,
    const float* __restrict__ ga2, const float* __restrict__ be2,
    const float* __restrict__ me2, const float* __restrict__ va2,
    unsigned short* __restrict__ outg, unsigned short* __restrict__ outt,
    unsigned short* __restrict__ outp)
{
  const int b = blockIdx.z, nt = blockIdx.x, ot = blockIdx.y;
  const int n0 = nt*64, o0 = ot*64;
  const int t = threadIdx.x, w = t>>6, l = t&63;
  __shared__ unsigned short xs[64][64];
  __shared__ unsigned short ws[3][64][64];
  __shared__ float sc_s[3][64], sh_s[3][64];
  if (t < 64){
    int o = o0 + t;
    float s0 = ga0[o]*rsqrtf(va0[o]+1e-5f);
    sc_s[0][t]=s0; sh_s[0][t]=be0[o]-me0[o]*s0+b0[o]*s0;
    float s1 = ga1[o]*rsqrtf(va1[o]+1e-5f);
    sc_s[1][t]=s1*LOG2E; sh_s[1][t]=(be1[o]-me1[o]*s1+b1[o]*s1)*LOG2E;
    float s2 = ga2[o]*rsqrtf(va2[o]+1e-5f);
    sc_s[2][t]=s2; sh_s[2][t]=be2[o]-me2[o]*s2+b2[o]*s2;
  }
  const f32x4 Z = {0.f,0.f,0.f,0.f};
  f32x4 acc[3][4];
  #pragma unroll
  for (int br=0;br<3;++br) for (int i=0;i<4;++i) acc[br][i] = Z;
  const float* Wt[3] = {w0, w1, w2};

  // prefetch registers for one k-chunk
  float4 xg0[2], xg1[2];      // [p2]: row cpr and cpr+1
  float4 wg[4][3];            // [p][br]
  const int cbase = 2*(t>>4);
  const int nb = (t&15)*4;
  const int q4 = (t&15)*4;

  // preload chunk 0
  #pragma unroll
  for (int p2=0;p2<2;++p2){
    const float* xr0 = x + ((size_t)b*CIN + p2*32 + cbase)*NSP + n0 + nb;
    xg0[p2] = *(const float4*)xr0;
    xg1[p2] = *(const float4*)(xr0 + NSP);
  }
  #pragma unroll
  for (int p=0;p<4;++p){
    int cw = p*16 + (t>>4);
    #pragma unroll
    for (int br=0;br<3;++br)
      wg[p][br] = *(const float4*)(Wt[br] + (size_t)(o0 + cw)*CIN + q4);
  }

  #pragma unroll
  for (int ci = 0; ci < 4; ++ci){
    __syncthreads();   // prior MFMA reads of LDS done
    // store prefetched regs -> LDS (packed cvt)
    #pragma unroll
    for (int p2=0;p2<2;++p2){
      int cpr = p2*32 + cbase;
      float aa[4] = {xg0[p2].x, xg0[p2].y, xg0[p2].z, xg0[p2].w};
      float bb[4] = {xg1[p2].x, xg1[p2].y, xg1[p2].z, xg1[p2].w};
      #pragma unroll
      for (int i=0;i<4;++i){
        int r = nb + i;
        *(unsigned*)&xs[r][swz(r, cpr)] = pk2h(aa[i], bb[i]);
      }
    }
    #pragma unroll
    for (int p=0;p<4;++p){
      int cw = p*16 + (t>>4);
      #pragma unroll
      for (int br=0;br<3;++br){
        float4 wv = wg[p][br];
        uint2 u; u.x = pk2h(wv.x, wv.y); u.y = pk2h(wv.z, wv.w);
        *(uint2*)&ws[br][cw][swz(cw, q4)] = u;
      }
    }
    // issue next chunk's loads (latency hidden under MFMA below)
    if (ci < 3){
      int kc = (ci+1)*64;
      #pragma unroll
      for (int p2=0;p2<2;++p2){
        const float* xr0 = x + ((size_t)b*CIN + kc + p2*32 + cbase)*NSP + n0 + nb;
        xg0[p2] = *(const float4*)xr0;
        xg1[p2] = *(const float4*)(xr0 + NSP);
      }
      #pragma unroll
      for (int p=0;p<4;++p){
        int cw = p*16 + (t>>4);
        #pragma unroll
        for (int br=0;br<3;++br)
          wg[p][br] = *(const float4*)(Wt[br] + (size_t)(o0 + cw)*CIN + kc + q4);
      }
    }
    __syncthreads();   // stores visible
    #pragma unroll
    for (int kf = 0; kf < 2; ++kf){
      int ko = kf*32 + (l>>4)*8;
      int wr = 16*w + (l&15);
      short8 wf0 = *(const short8*)&ws[0][wr][swz(wr, ko)];
      short8 wf1 = *(const short8*)&ws[1][wr][swz(wr, ko)];
      short8 wf2 = *(const short8*)&ws[2][wr][swz(wr, ko)];
      #pragma unroll
      for (int nf = 0; nf < 4; ++nf){
        int xr = 16*nf + (l&15);
        short8 xf = *(const short8*)&xs[xr][swz(xr, ko)];
        acc[0][nf] = mfmah(wf0, xf, acc[0][nf]);   // orient0 (g)
        acc[1][nf] = mfmah(xf, wf1, acc[1][nf]);   // orient1 (theta)
        acc[2][nf] = mfmah(xf, wf2, acc[2][nf]);   // orient1 (phi)
      }
    }
  }
  // g epilogue (orient0, kperm-permuted column order)
  #pragma unroll
  for (int j=0;j<4;++j){
    int ol = 16*w + (l>>4)*4 + j;
    float s = sc_s[0][ol], sh = sh_s[0][ol];
    #pragma unroll
    for (int nf=0;nf<4;++nf){
      int n = n0 + 16*nf + (l&15);
      int nst = (n & ~31) | kperm(n & 31);
      float v = fmaxf(acc[0][nf][j]*s + sh, 0.f);
      outg[((size_t)b*ICH + o0 + ol)*NSP + nst] = f2h(v);
    }
  }
  // theta/phi epilogue (orient1)
  {
    int ol = 16*w + (l&15);
    float s1 = sc_s[1][ol], sh1 = sh_s[1][ol];
    float s2 = sc_s[2][ol], sh2 = sh_s[2][ol];
    #pragma unroll
    for (int nf=0; nf<4; ++nf)
      #pragma unroll
      for (int j=0;j<4;++j){
        int n = n0 + 16*nf + (l>>4)*4 + j;
        float v1 = fmaxf(acc[1][nf][j]*s1 + sh1, 0.f);
        float v2 = fmaxf(acc[2][nf][j]*s2 + sh2, 0.f);
        outt[((size_t)b*NSP + n)*ICH + o0 + ol] = f2h(v1);
        outp[((size_t)b*NSP + n)*ICH + o0 + ol] = f2h(v2);
      }
  }
}

// ---------------------------------------------------------------------------
// Flash attention, 32x32x16 MFMA, 4 waves x 32 Q rows. Softmax/PV interleaved:
// exp(sc0)+pack -> PV-a, exp(sc1)+pack -> PV-b (trans pipe overlaps matrix).
// ---------------------------------------------------------------------------
__global__ __launch_bounds__(256, 2) void attn_k(
  const unsigned short* __restrict__ thp, const unsigned short* __restrict__ php,
  const unsigned short* __restrict__ gb, unsigned short* __restrict__ ypart,
  float* __restrict__ ml)
{
  const int bx = blockIdx.x;
  const int xcd = bx & 7, jj = bx >> 3;
  const int combo = xcd*2 + (jj>>5);
  const int qt = jj & 31;
  const int b = combo & 3, s = combo >> 2;
  const int n0 = qt*128;
  const int t = threadIdx.x, w = t>>6, l = t&63;
  const int hi = l>>5, ln = l&31;

  __shared__ unsigned short kb[2][8192];   // K double buffer [64][128]
  __shared__ unsigned short vb[2][8192];   // V double buffer [128][64]

  // ---- stage Q halves through kb[0]/kb[1], preload 8 B-fragments ----
  stage_nc(thp + ((size_t)b*NSP + n0      )*ICH, &kb[0][0], w, l);
  stage_nc(thp + ((size_t)b*NSP + n0 + 64 )*ICH, &kb[1][0], w, l);
  __syncthreads();
  short8 qf[8];
  {
    const unsigned short* qsrc = (w >> 1) ? &kb[1][0] : &kb[0][0];
    int r = 32*(w & 1) + ln;
    #pragma unroll
    for (int kc=0;kc<8;++kc)
      qf[kc] = *(const short8*)&qsrc[r*128 + swzK(r, kc*16 + 8*hi)];
  }
  __syncthreads();

  f32x16 oa[4];
  #pragma unroll
  for (int i=0;i<4;++i)
    #pragma unroll
    for (int j=0;j<16;++j) oa[i][j] = 0.f;
  float mr = -1e30f, lr = 0.f;
  unsigned pk[16];

  const int tile0 = s*TILES_PER_SPLIT;

  // ---- hoisted per-lane staging pointers ----
  const unsigned short* kp[4];
  const unsigned short* vp[4];
  {
    const unsigned short* kbase = php + ((size_t)b*NSP + tile0*64)*ICH;
    const unsigned short* vbase = gb + (size_t)b*ICH*NSP + tile0*64;
    #pragma unroll
    for (int i=0;i<4;++i){
      int rl = 16*w + 4*i + (l>>4);
      int eg = ((l&15)*8) ^ ((rl&15)<<3);
      kp[i] = kbase + (size_t)rl*128 + eg;
      int cl = 32*w + 8*i + (l>>3);
      int me = ((l&7)*8) ^ ((cl&7)<<3);
      vp[i] = vbase + (size_t)cl*NSP + me;
    }
  }
  // prologue: stage tile0 into buffer 0
  {
    unsigned short* kd = &kb[0][0] + w*2048;
    unsigned short* vd = &vb[0][0] + w*2048;
    #pragma unroll
    for (int i=0;i<4;++i){
      gload_lds16(kp[i], kd + i*512); kp[i] += 64*ICH;
      gload_lds16(vp[i], vd + i*512); vp[i] += 64;
    }
  }
  __syncthreads();
  int cur = 0;

  for (int it = 0; it < TILES_PER_SPLIT; ++it){
    // (A) prefetch next K+V
    if (it < TILES_PER_SPLIT-1){
      unsigned short* kd = &kb[cur^1][0] + w*2048;
      unsigned short* vd = &vb[cur^1][0] + w*2048;
      #pragma unroll
      for (int i=0;i<4;++i){
        gload_lds16(kp[i], kd + i*512); kp[i] += 64*ICH;
        gload_lds16(vp[i], vd + i*512); vp[i] += 64;
      }
    }

    // (B) swapped QK^T: sc rows = m, cols = n. 16 mfma_32x32x16.
    f32x16 sc0, sc1;
    #pragma unroll
    for (int j=0;j<16;++j){ sc0[j]=0.f; sc1[j]=0.f; }
    __builtin_amdgcn_s_setprio(1);
    #pragma unroll
    for (int kc=0;kc<8;++kc){
      int eo = kc*16 + 8*hi;
      short8 a0 = *(const short8*)&kb[cur][(ln     )*128 + swzK(ln,      eo)];
      short8 a1 = *(const short8*)&kb[cur][(32 + ln)*128 + swzK(32 + ln, eo)];
      sc0 = mfma32(a0, qf[kc], sc0);
      sc1 = mfma32(a1, qf[kc], sc1);
    }
    __builtin_amdgcn_s_setprio(0);

    // (C1) max reduce + deferred rescale
    {
      float t0 = fmaxf(fmaxf(sc0[0],sc0[1]),  fmaxf(sc0[2],sc0[3]));
      float t1 = fmaxf(fmaxf(sc0[4],sc0[5]),  fmaxf(sc0[6],sc0[7]));
      float t2 = fmaxf(fmaxf(sc0[8],sc0[9]),  fmaxf(sc0[10],sc0[11]));
      float t3 = fmaxf(fmaxf(sc0[12],sc0[13]),fmaxf(sc0[14],sc0[15]));
      float t4 = fmaxf(fmaxf(sc1[0],sc1[1]),  fmaxf(sc1[2],sc1[3]));
      float t5 = fmaxf(fmaxf(sc1[4],sc1[5]),  fmaxf(sc1[6],sc1[7]));
      float t6 = fmaxf(fmaxf(sc1[8],sc1[9]),  fmaxf(sc1[10],sc1[11]));
      float t7 = fmaxf(fmaxf(sc1[12],sc1[13]),fmaxf(sc1[14],sc1[15]));
      float mx = fmaxf(fmaxf(fmaxf(t0,t1),fmaxf(t2,t3)),
                       fmaxf(fmaxf(t4,t5),fmaxf(t6,t7)));
      mx = fmaxf(mx, __shfl_xor(mx, 32));
      if (__any(mx - mr > 11.5f)){   // defer-max (log2 units)
        float mn = fmaxf(mr, mx);
        float al = fexp2(mr - mn);
        mr = mn; lr *= al;
        #pragma unroll
        for (int j=0;j<16;++j){
          int rowj = (j&3) + 8*(j>>2) + 4*hi;
          float alj = __shfl(al, rowj);
          #pragma unroll
          for (int ct=0;ct<4;++ct) oa[ct][j] *= alj;
        }
      }
    }

    float sA=0.f, sB=0.f, sC=0.f, sD=0.f;
    // (C2a) exp sc0 + pack pk[0..7]
    #pragma unroll
    for (int r=0;r<16;r+=4){
      sc0[r]   = fexp2(sc0[r]  -mr); sA += sc0[r];
      sc0[r+1] = fexp2(sc0[r+1]-mr); sB += sc0[r+1];
      sc0[r+2] = fexp2(sc0[r+2]-mr); sC += sc0[r+2];
      sc0[r+3] = fexp2(sc0[r+3]-mr); sD += sc0[r+3];
    }
    #pragma unroll
    for (int s2=0;s2<2;++s2)
      #pragma unroll
      for (int q=0;q<4;++q)
        pk[s2*4+q] = pk2h(sc0[8*s2+2*q], sc0[8*s2+2*q+1]);
    // (D-a) PV for sc0's m-rows (overlappable with C2b below)
    __builtin_amdgcn_s_setprio(1);
    #pragma unroll
    for (int s2=0;s2<2;++s2){
      union { unsigned u[4]; short8 s8; } au;
      #pragma unroll
      for (int q=0;q<4;++q) au.u[q] = pk[4*s2+q];
      int eo = 16*s2 + 8*hi;
      #pragma unroll
      for (int ct=0;ct<4;++ct){
        int cr = 32*ct + ln;
        short8 bv = *(const short8*)&vb[cur][cr*64 + swz(cr, eo)];
        oa[ct] = mfma32(au.s8, bv, oa[ct]);
      }
    }
    __builtin_amdgcn_s_setprio(0);
    // (C2b) exp sc1 + pack pk[8..15]
    #pragma unroll
    for (int r=0;r<16;r+=4){
      sc1[r]   = fexp2(sc1[r]  -mr); sA += sc1[r];
      sc1[r+1] = fexp2(sc1[r+1]-mr); sB += sc1[r+1];
      sc1[r+2] = fexp2(sc1[r+2]-mr); sC += sc1[r+2];
      sc1[r+3] = fexp2(sc1[r+3]-mr); sD += sc1[r+3];
    }
    #pragma unroll
    for (int s2=0;s2<2;++s2)
      #pragma unroll
      for (int q=0;q<4;++q)
        pk[8+s2*4+q] = pk2h(sc1[8*s2+2*q], sc1[8*s2+2*q+1]);
    lr += (sA + sB) + (sC + sD);
    // (D-b) PV for sc1's m-rows
    __builtin_amdgcn_s_setprio(1);
    #pragma unroll
    for (int s2=0;s2<2;++s2){
      union { unsigned u[4]; short8 s8; } au;
      #pragma unroll
      for (int q=0;q<4;++q) au.u[q] = pk[8+4*s2+q];
      int eo = 32 + 16*s2 + 8*hi;
      #pragma unroll
      for (int ct=0;ct<4;++ct){
        int cr = 32*ct + ln;
        short8 bv = *(const short8*)&vb[cur][cr*64 + swz(cr, eo)];
        oa[ct] = mfma32(au.s8, bv, oa[ct]);
      }
    }
    __builtin_amdgcn_s_setprio(0);

    __syncthreads();
    cur ^= 1;
  }

  // ---- epilogue: combine partner sums, normalize, write ----
  lr += __shfl_xor(lr, 32);
  float invl = 1.f / lr;
  #pragma unroll
  for (int j=0;j<16;++j){
    int rowj = (j&3) + 8*(j>>2) + 4*hi;
    float invj = __shfl(invl, rowj);
    int n = n0 + 32*w + rowj;
    #pragma unroll
    for (int ct=0;ct<4;++ct){
      int c = 32*ct + ln;
      ypart[(((size_t)s*4 + b)*NSP + n)*ICH + c] = f2h(oa[ct][j]*invj);
    }
  }
  if (l < 32){
    int n = n0 + 32*w + l;
    ml[(((size_t)s*4 + b)*NSP + n)*2 + 0] = mr;
    ml[(((size_t)s*4 + b)*NSP + n)*2 + 1] = lr;
  }
}

// ---------------------------------------------------------------------------
// Final conv + fused split-combine, 2 o-tiles per block; packed W2 staging.
// ---------------------------------------------------------------------------
__global__ __launch_bounds__(256) void final_k2(
  const unsigned short* __restrict__ ypart, const float* __restrict__ ml,
  const float* __restrict__ x, const float* __restrict__ Wm,
  const float* __restrict__ bias, const float* __restrict__ gamma,
  const float* __restrict__ beta, const float* __restrict__ mean,
  const float* __restrict__ var, float* __restrict__ out)
{
  const int b = blockIdx.z, oth = blockIdx.y, nt = blockIdx.x;
  const int n0 = nt*64, obase = oth*128;
  const int t = threadIdx.x, w = t>>6, l = t&63;
  __shared__ unsigned short ys[64][128];
  __shared__ unsigned short w2s[64][128];
  __shared__ float wc[SPLITS][64];
  __shared__ float sc_s[128], sh_s[128];
  if (t < 128){
    int o = obase + t;
    float s = gamma[o]*rsqrtf(var[o]+1e-5f);
    sc_s[t]=s; sh_s[t]=beta[o]-mean[o]*s+bias[o]*s;
  } else if (t < 192){
    int r = t - 128, n = n0 + r;
    float mv[SPLITS], lv[SPLITS];
    #pragma unroll
    for (int s=0;s<SPLITS;++s){
      mv[s] = ml[(((size_t)s*4 + b)*NSP + n)*2 + 0];
      lv[s] = ml[(((size_t)s*4 + b)*NSP + n)*2 + 1];
    }
    float M = fmaxf(fmaxf(mv[0],mv[1]), fmaxf(mv[2],mv[3]));
    float wsum = 0.f, wv[SPLITS];
    #pragma unroll
    for (int s=0;s<SPLITS;++s){ wv[s] = lv[s]*exp2f(mv[s]-M); wsum += wv[s]; }
    float inv = 1.f/wsum;
    #pragma unroll
    for (int s=0;s<SPLITS;++s) wc[s][r] = wv[s]*inv;
  }
  __syncthreads();
  // combine ypart -> ys (once)
  #pragma unroll
  for (int p=0;p<4;++p){
    int id = p*256 + t, r = id>>4, c8 = (id&15)*8;
    float accv[8] = {0,0,0,0,0,0,0,0};
    #pragma unroll
    for (int s=0;s<SPLITS;++s){
      short8 v = *(const short8*)(ypart + (((size_t)s*4 + b)*NSP + n0 + r)*ICH + c8);
      float wgt = wc[s][r];
      #pragma unroll
      for (int i=0;i<8;++i) accv[i] += wgt * h2f(((unsigned short*)&v)[i]);
    }
    uint2 hv;
    hv.x = pk2h(accv[0], accv[1]);
    hv.y = pk2h(accv[2], accv[3]);
    uint2 hv2;
    hv2.x = pk2h(accv[4], accv[5]);
    hv2.y = pk2h(accv[6], accv[7]);
    *(uint2*)&ys[r][swz(r,c8)] = hv;
    *(uint2*)&ys[r][swz(r,c8)+4] = hv2;
  }

  const f32x4 Z = {0.f,0.f,0.f,0.f};
  #pragma unroll
  for (int ot2 = 0; ot2 < 2; ++ot2){
    const int o0 = obase + ot2*64;
    #pragma unroll
    for (int p=0;p<4;++p){
      int id = p*256 + t, r = id>>4, c8 = (id&15)*8;
      float4 u0 = *(const float4*)(Wm + (size_t)(o0 + r)*ICH + c8);
      float4 u1 = *(const float4*)(Wm + (size_t)(o0 + r)*ICH + c8 + 4);
      uint2 u; u.x = pk2h(u0.x, u0.y); u.y = pk2h(u0.z, u0.w);
      uint2 v2; v2.x = pk2h(u1.x, u1.y); v2.y = pk2h(u1.z, u1.w);
      *(uint2*)&w2s[r][swz(r,c8)] = u;
      *(uint2*)&w2s[r][swz(r,c8)+4] = v2;
    }
    __syncthreads();
    f32x4 acc[4];
    #pragma unroll
    for (int i=0;i<4;++i) acc[i]=Z;
    #pragma unroll
    for (int kf=0;kf<4;++kf){
      int ko = kf*32 + (l>>4)*8;
      int wr = 16*w + (l&15);
      short8 a = *(const short8*)&w2s[wr][swz(wr,ko)];
      #pragma unroll
      for (int nf=0;nf<4;++nf){
        int yr = 16*nf + (l&15);
        short8 bb = *(const short8*)&ys[yr][swz(yr,ko)];
        acc[nf] = mfmah(a, bb, acc[nf]);
      }
    }
    #pragma unroll
    for (int j=0;j<4;++j){
      int ol = 16*w + (l>>4)*4 + j;
      float s = sc_s[ot2*64 + ol], sh = sh_s[ot2*64 + ol];
      #pragma unroll
      for (int nf=0;nf<4;++nf){
        int n = n0 + 16*nf + (l&15);
        size_t idx = ((size_t)b*CIN + o0 + ol)*NSP + n;
        out[idx] = acc[nf][j]*s + sh + x[idx];
      }
    }
    __syncthreads();
  }
}

extern "C" void kernel_launch(void* const* d_in, const int* in_sizes, int n_in,
                              void* d_out, int out_size, void* d_ws, size_t ws_size,
                              hipStream_t stream){
  const float* x    = (const float*)d_in[0];
  const float* g_w  = (const float*)d_in[1];
  const float* g_b  = (const float*)d_in[2];
  const float* g_ga = (const float*)d_in[3];
  const float* g_be = (const float*)d_in[4];
  const float* g_me = (const float*)d_in[5];
  const float* g_va = (const float*)d_in[6];
  const float* t_w  = (const float*)d_in[7];
  const float* t_b  = (const float*)d_in[8];
  const float* t_ga = (const float*)d_in[9];
  const float* t_be = (const float*)d_in[10];
  const float* t_me = (const float*)d_in[11];
  const float* t_va = (const float*)d_in[12];
  const float* p_w  = (const float*)d_in[13];
  const float* p_b  = (const float*)d_in[14];
  const float* p_ga = (const float*)d_in[15];
  const float* p_be = (const float*)d_in[16];
  const float* p_me = (const float*)d_in[17];
  const float* p_va = (const float*)d_in[18];
  const float* w_w  = (const float*)d_in[19];
  const float* w_b  = (const float*)d_in[20];
  const float* w_ga = (const float*)d_in[21];
  const float* w_be = (const float*)d_in[22];
  const float* w_me = (const float*)d_in[23];
  const float* w_va = (const float*)d_in[24];

  char* ws = (char*)d_ws;
  const size_t SEG = (size_t)4*NSP*ICH*sizeof(unsigned short);   // 4 MB
  unsigned short* th_t  = (unsigned short*)(ws);
  unsigned short* ph_t  = (unsigned short*)(ws + SEG);
  unsigned short* g_cn  = (unsigned short*)(ws + 2*SEG);
  unsigned short* ypart = (unsigned short*)(ws + 3*SEG);
  float*          mlb   = (float*)(ws + 3*SEG + SPLITS*SEG);

  dim3 blk(256,1,1);
  conv_fused_k<<<dim3(64,2,4), blk, 0, stream>>>(
      x,
      g_w, g_b, g_ga, g_be, g_me, g_va,
      t_w, t_b, t_ga, t_be, t_me, t_va,
      p_w, p_b, p_ga, p_be, p_me, p_va,
      g_cn, th_t, ph_t);
  attn_k<<<dim3(512,1,1), blk, 0, stream>>>(th_t, ph_t, g_cn, ypart, mlb);
  final_k2<<<dim3(64,2,4), blk, 0, stream>>>(ypart, mlb, x, w_w, w_b, w_ga, w_be, w_me, w_va, (float*)d_out);
}